// Round 1
// baseline (8066.250 us; speedup 1.0000x reference)
//
#include <hip/hip_runtime.h>
#include <hip/hip_bf16.h>

#define NA 150000
#define NT 200000
#define IND 64
#define HIDD 32
#define NHEAD 4
#define DIMH 8
#define E_AT 1000000
#define E_TA 1000000
#define E_AA 500000

// ---------- dtype-flexible load: flag==1 -> fp32, flag==0 -> bf16 ----------
__device__ __forceinline__ float ldf(const void* p, long i, int f32) {
    if (f32) return ((const float*)p)[i];
    unsigned int u = ((const unsigned short*)p)[i];
    union { unsigned int ui; float f; } v; v.ui = u << 16;
    return v.f;
}

// ---------- detect whether float inputs are fp32 (1) or bf16 (0) ----------
// Reading fp32 N(0,1) data as ushorts: low halves are float mantissa bits ->
// bf16 exponent field ~uniform -> ~87% "wild" magnitudes. Genuine bf16 N(0,1)
// has exponents in a narrow band -> ~0 wild.
__global__ void k_detect(const void* __restrict__ x, int* __restrict__ flag) {
    __shared__ int cnt;
    if (threadIdx.x == 0) cnt = 0;
    __syncthreads();
    const unsigned short* u = (const unsigned short*)x;
    int wild = 0;
    for (int i = threadIdx.x; i < 4096; i += 256) {
        unsigned short v = u[i];
        int e = (v >> 7) & 0xFF;
        if (e > 133 || (e != 0 && e < 100)) wild++;           // |v|>~64 or <~2^-27
        else if (e == 0 && (v & 0x7F)) wild++;                // subnormal junk
    }
    atomicAdd(&cnt, wild);
    __syncthreads();
    if (threadIdx.x == 0) *flag = (cnt > 1024) ? 1 : 0;
}

// ---------- projection: H[n,32] = X[n,:K] @ W[K,32] + B ----------
__global__ void k_proj(const void* __restrict__ X, int x_is_ws,
                       const void* __restrict__ W, int wOff,
                       const void* __restrict__ B, int bOff,
                       float* __restrict__ H, int N, int K,
                       const int* __restrict__ flagp) {
    int idx = blockIdx.x * blockDim.x + threadIdx.x;
    if (idx >= N * 32) return;
    int f32 = *flagp;
    int xf = x_is_ws ? 1 : f32;
    int n = idx >> 5, m = idx & 31;
    float acc = ldf(B, bOff + m, f32);
    long xo = (long)n * K;
    for (int k = 0; k < K; k++)
        acc += ldf(X, xo + k, xf) * ldf(W, wOff + (long)k * 32 + m, f32);
    H[idx] = acc;
}

// ---------- per-node attention coefficient: out[n,h] = <H[n,h,:], att[h,:]> ----------
__global__ void k_alpha(const float* __restrict__ H, int N,
                        const void* __restrict__ att, int attOff,
                        float* __restrict__ out, const int* __restrict__ flagp) {
    int idx = blockIdx.x * blockDim.x + threadIdx.x;
    if (idx >= N * 4) return;
    int f32 = *flagp;
    int n = idx >> 2, h = idx & 3;
    float acc = 0.f;
    const float* hp = &H[(long)n * 32 + h * 8];
#pragma unroll
    for (int d = 0; d < 8; d++) acc += hp[d] * ldf(att, attOff + h * 8 + d, f32);
    out[idx] = acc;
}

// ---------- edge pass: S[dst,h] += e; O[dst,h,:] += e * Hs[src,h,:] ----------
__global__ void k_edge(const int* __restrict__ src, const int* __restrict__ dst, int E,
                       const float* __restrict__ as_, const float* __restrict__ ad_,
                       const float* __restrict__ Hs,
                       float* __restrict__ S, float* __restrict__ O) {
    int idx = blockIdx.x * blockDim.x + threadIdx.x;
    if (idx >= E * 4) return;
    int e = idx >> 2, h = idx & 3;
    int s = src[e], d = dst[e];
    float l = as_[(long)s * 4 + h] + ad_[(long)d * 4 + h];
    l = (l >= 0.f) ? l : 0.2f * l;           // leaky_relu, slope 0.2
    float ev = expf(l);                      // no max-subtraction needed (|l| small)
    atomicAdd(&S[(long)d * 4 + h], ev);
    const float* hs = &Hs[(long)s * 32 + h * 8];
    float* o = &O[(long)d * 32 + h * 8];
#pragma unroll
    for (int k = 0; k < 8; k++) atomicAdd(&o[k], ev * hs[k]);
}

// ---------- normalize + relu in place ----------
__global__ void k_norm_relu(float* __restrict__ O, const float* __restrict__ S, int N) {
    int idx = blockIdx.x * blockDim.x + threadIdx.x;
    if (idx >= N * 32) return;
    int n = idx >> 5, h = (idx >> 3) & 3;
    float v = O[idx] / (S[(long)n * 4 + h] + 1e-16f);
    O[idx] = (v > 0.f) ? v : 0.f;
}

// ---------- semantic reduce: accum[f] += sum_n tanh(O[n,:]@kW[:,f] + kb[f]) ----------
__global__ void k_sem_reduce(const float* __restrict__ O, int N,
                             const void* __restrict__ kWp, int kwOff,
                             const void* __restrict__ kbp, int kbOff,
                             float* __restrict__ accum, const int* __restrict__ flagp) {
    int f32 = *flagp;
    __shared__ float w[1056];   // 32x32 weights + 32 bias
    __shared__ float sacc[32];
    for (int i = threadIdx.x; i < 1024; i += blockDim.x) w[i] = ldf(kWp, kwOff + i, f32);
    if (threadIdx.x < 32) {
        w[1024 + threadIdx.x] = ldf(kbp, kbOff + threadIdx.x, f32);
        sacc[threadIdx.x] = 0.f;
    }
    __syncthreads();
    int n = blockIdx.x * blockDim.x + threadIdx.x;
    float y[32];
    if (n < N) {
        float x[32];
#pragma unroll
        for (int k = 0; k < 32; k++) x[k] = O[(long)n * 32 + k];
#pragma unroll
        for (int f = 0; f < 32; f++) {
            float acc = w[1024 + f];
#pragma unroll
            for (int k = 0; k < 32; k++) acc += x[k] * w[k * 32 + f];
            y[f] = tanhf(acc);
        }
    } else {
#pragma unroll
        for (int f = 0; f < 32; f++) y[f] = 0.f;
    }
    // wave-level butterfly reduce each f, then one LDS atomic per wave
#pragma unroll
    for (int f = 0; f < 32; f++) {
        float v = y[f];
        for (int o = 32; o > 0; o >>= 1) v += __shfl_xor(v, o, 64);
        if ((threadIdx.x & 63) == 0) atomicAdd(&sacc[f], v);
    }
    __syncthreads();
    if (threadIdx.x < 32) atomicAdd(&accum[threadIdx.x], sacc[threadIdx.x]);
}

// ---------- semantic attention weights (R=2 softmax) ----------
__global__ void k_sem_attn(const float* __restrict__ accum, float Ninv,
                           const void* __restrict__ q, int qOff,
                           float* __restrict__ attn, const int* __restrict__ flagp) {
    if (threadIdx.x == 0) {
        int f32 = *flagp;
        float s0 = 0.f, s1 = 0.f;
        for (int f = 0; f < 32; f++) {
            float qf = ldf(q, qOff + f, f32);
            s0 += accum[f] * Ninv * qf;
            s1 += accum[32 + f] * Ninv * qf;
        }
        float m = fmaxf(s0, s1);
        float e0 = expf(s0 - m), e1 = expf(s1 - m);
        float inv = 1.f / (e0 + e1);
        attn[0] = e0 * inv;
        attn[1] = e1 * inv;
    }
}

// ---------- combine relations with semantic weights (+relu, identity here) ----------
__global__ void k_combine(const float* __restrict__ o1, const float* __restrict__ o2,
                          const float* __restrict__ attn, float* __restrict__ out, int N) {
    int idx = blockIdx.x * blockDim.x + threadIdx.x;
    if (idx >= N * 32) return;
    float v = attn[0] * o1[idx] + attn[1] * o2[idx];
    out[idx] = (v > 0.f) ? v : 0.f;
}

// ---------- final linear: out[n,c] = A[n,:]@linW[:,c] + linb[c] ----------
__global__ void k_final(const float* __restrict__ A,
                        const void* __restrict__ linW, const void* __restrict__ linb,
                        void* __restrict__ out, int N, const int* __restrict__ flagp) {
    int idx = blockIdx.x * blockDim.x + threadIdx.x;
    if (idx >= N * 2) return;
    int f32 = *flagp;
    int n = idx >> 1, c = idx & 1;
    float acc = ldf(linb, c, f32);
    for (int f = 0; f < 32; f++) acc += A[(long)n * 32 + f] * ldf(linW, f * 2 + c, f32);
    if (f32) ((float*)out)[idx] = acc;
    else ((__hip_bfloat16*)out)[idx] = __float2bfloat16(acc);
}

static inline int gblocks(long n) { return (int)((n + 255) / 256); }

extern "C" void kernel_launch(void* const* d_in, const int* in_sizes, int n_in,
                              void* d_out, int out_size, void* d_ws, size_t ws_size,
                              hipStream_t stream) {
    const void* x_addr = d_in[0];
    const void* x_tx   = d_in[1];
    const int* eat_s = (const int*)d_in[2];
    const int* eat_d = (const int*)d_in[3];
    const int* eta_s = (const int*)d_in[4];
    const int* eta_d = (const int*)d_in[5];
    const int* eaa_s = (const int*)d_in[6];
    const int* eaa_d = (const int*)d_in[7];
    const void* pW1    = d_in[8];
    const void* pb1    = d_in[9];
    const void* pW23   = d_in[10];
    const void* pb23   = d_in[11];
    const void* attS   = d_in[12];
    const void* attD   = d_in[13];
    const void* kW     = d_in[14];
    const void* kb     = d_in[15];
    const void* qv     = d_in[16];
    const void* linW   = d_in[17];
    const void* linb   = d_in[18];

    const size_t NA32 = (size_t)NA * 32, NT32 = (size_t)NT * 32;
    const size_t NA4 = (size_t)NA * 4, NT4 = (size_t)NT * 4;

    float* ws    = (float*)d_ws;
    float* abufA = ws;
    float* abufB = abufA + NA32;
    float* h_a   = abufB + NA32;
    float* h_t   = h_a + NA32;
    float* as0   = h_t + NT32;
    float* ad1   = as0 + NA4;
    float* as2   = ad1 + NA4;
    float* ad2   = as2 + NA4;
    float* as1   = ad2 + NA4;
    float* ad0   = as1 + NT4;
    int*   flagp = (int*)(ad0 + NT4);
    // zero region (memset once per layer):
    float* zstart = (float*)(flagp + 16);
    float* o_a1  = zstart;
    float* o_a2  = o_a1 + NA32;
    float* tbufA = o_a2 + NA32;
    float* tbufB = tbufA + NT32;
    float* s_a1  = tbufB + NT32;
    float* s_a2  = s_a1 + NA4;
    float* s_tx  = s_a2 + NA4;
    float* sem   = s_tx + NT4;             // 64 accum + 2 attn
    size_t zbytes = (size_t)((sem + 66) - zstart) * sizeof(float);

    k_detect<<<1, 256, 0, stream>>>(x_addr, flagp);

    float* a_cur = nullptr;
    float* t_cur = nullptr;
    float* o_tx_buf[3] = { tbufA, tbufB, tbufA };

    for (int l = 0; l < 3; l++) {
        // 1) projections (consume a_cur/t_cur BEFORE the memset below)
        if (l == 0) {
            k_proj<<<gblocks(NA32), 256, 0, stream>>>(x_addr, 0, pW1, 0,    pb1, 0,  h_a, NA, 64, flagp);
            k_proj<<<gblocks(NT32), 256, 0, stream>>>(x_tx,   0, pW1, 2048, pb1, 32, h_t, NT, 64, flagp);
        } else {
            int wi = (l - 1) * 2;
            k_proj<<<gblocks(NA32), 256, 0, stream>>>(a_cur, 1, pW23, (wi + 0) * 1024, pb23, (wi + 0) * 32, h_a, NA, 32, flagp);
            k_proj<<<gblocks(NT32), 256, 0, stream>>>(t_cur, 1, pW23, (wi + 1) * 1024, pb23, (wi + 1) * 32, h_t, NT, 32, flagp);
        }
        // 2) zero accumulators (o_*, tbufs, s_*, sem)
        (void)hipMemsetAsync(zstart, 0, zbytes, stream);
        // 3) per-node attention coefficients for the 3 relations
        k_alpha<<<gblocks(NA4), 256, 0, stream>>>(h_a, NA, attS, l * 96 + 0,  as0, flagp);
        k_alpha<<<gblocks(NT4), 256, 0, stream>>>(h_t, NT, attD, l * 96 + 0,  ad0, flagp);
        k_alpha<<<gblocks(NT4), 256, 0, stream>>>(h_t, NT, attS, l * 96 + 32, as1, flagp);
        k_alpha<<<gblocks(NA4), 256, 0, stream>>>(h_a, NA, attD, l * 96 + 32, ad1, flagp);
        k_alpha<<<gblocks(NA4), 256, 0, stream>>>(h_a, NA, attS, l * 96 + 64, as2, flagp);
        k_alpha<<<gblocks(NA4), 256, 0, stream>>>(h_a, NA, attD, l * 96 + 64, ad2, flagp);
        // 4) edge scatter (unnormalized)
        float* o_tx = o_tx_buf[l];
        k_edge<<<gblocks((long)E_AT * 4), 256, 0, stream>>>(eat_s, eat_d, E_AT, as0, ad0, h_a, s_tx, o_tx);
        k_edge<<<gblocks((long)E_TA * 4), 256, 0, stream>>>(eta_s, eta_d, E_TA, as1, ad1, h_t, s_a1, o_a1);
        k_edge<<<gblocks((long)E_AA * 4), 256, 0, stream>>>(eaa_s, eaa_d, E_AA, as2, ad2, h_a, s_a2, o_a2);
        // 5) normalize + relu
        k_norm_relu<<<gblocks(NT32), 256, 0, stream>>>(o_tx, s_tx, NT);
        k_norm_relu<<<gblocks(NA32), 256, 0, stream>>>(o_a1, s_a1, NA);
        k_norm_relu<<<gblocks(NA32), 256, 0, stream>>>(o_a2, s_a2, NA);
        // 6) semantic attention over {o_a1, o_a2} (tx side is identity, R=1)
        k_sem_reduce<<<gblocks(NA), 256, 0, stream>>>(o_a1, NA, kW, l * 1024, kb, l * 32, sem,      flagp);
        k_sem_reduce<<<gblocks(NA), 256, 0, stream>>>(o_a2, NA, kW, l * 1024, kb, l * 32, sem + 32, flagp);
        k_sem_attn<<<1, 64, 0, stream>>>(sem, 1.0f / NA, qv, l * 32, sem + 64, flagp);
        float* a_next = (l & 1) ? abufB : abufA;
        k_combine<<<gblocks(NA32), 256, 0, stream>>>(o_a1, o_a2, sem + 64, a_next, NA);
        a_cur = a_next;
        t_cur = o_tx;
    }
    k_final<<<gblocks((long)NA * 2), 256, 0, stream>>>(a_cur, linW, linb, d_out, NA, flagp);
}

// Round 2
// 2021.836 us; speedup vs baseline: 3.9896x; 3.9896x over previous
//
#include <hip/hip_runtime.h>
#include <hip/hip_bf16.h>

#define NA 150000
#define NT 200000
#define E_AT 1000000
#define E_TA 1000000
#define E_AA 500000

// ---------- dtype-flexible load: flag==1 -> fp32, flag==0 -> bf16 ----------
__device__ __forceinline__ float ldf(const void* p, long i, int f32) {
    if (f32) return ((const float*)p)[i];
    unsigned int u = ((const unsigned short*)p)[i];
    union { unsigned int ui; float f; } v; v.ui = u << 16;
    return v.f;
}

// ---------- detect fp32 (1) vs bf16 (0) float inputs ----------
__global__ void k_detect(const void* __restrict__ x, int* __restrict__ flag) {
    __shared__ int cnt;
    if (threadIdx.x == 0) cnt = 0;
    __syncthreads();
    const unsigned short* u = (const unsigned short*)x;
    int wild = 0;
    for (int i = threadIdx.x; i < 4096; i += 256) {
        unsigned short v = u[i];
        int e = (v >> 7) & 0xFF;
        if (e > 133 || (e != 0 && e < 100)) wild++;
        else if (e == 0 && (v & 0x7F)) wild++;
    }
    atomicAdd(&cnt, wild);
    __syncthreads();
    if (threadIdx.x == 0) *flag = (cnt > 1024) ? 1 : 0;
}

// ---------- projection: H[n,32] = X[n,:K] @ W[K,32] + B ----------
__global__ void k_proj(const void* __restrict__ X, int x_is_ws,
                       const void* __restrict__ W, int wOff,
                       const void* __restrict__ B, int bOff,
                       float* __restrict__ H, int N, int K,
                       const int* __restrict__ flagp) {
    int idx = blockIdx.x * blockDim.x + threadIdx.x;
    if (idx >= N * 32) return;
    int f32 = *flagp;
    int xf = x_is_ws ? 1 : f32;
    int n = idx >> 5, m = idx & 31;
    float acc = ldf(B, bOff + m, f32);
    long xo = (long)n * K;
    for (int k = 0; k < K; k++)
        acc += ldf(X, xo + k, xf) * ldf(W, wOff + (long)k * 32 + m, f32);
    H[idx] = acc;
}

// ---------- per-node attention coeffs, addr nodes: as0, ad1, as2, ad2 ----------
// att layout: [layer, edge_type, H, D] -> l*96 + e*32 + h*8 + d
__global__ void k_alpha_addr(const float* __restrict__ H,
                             const void* __restrict__ attS, const void* __restrict__ attD,
                             int lBase, float* __restrict__ as0, float* __restrict__ ad1,
                             float* __restrict__ as2, float* __restrict__ ad2,
                             const int* __restrict__ flagp) {
    int idx = blockIdx.x * blockDim.x + threadIdx.x;
    if (idx >= NA * 4) return;
    int f32 = *flagp;
    int n = idx >> 2, h = idx & 3;
    const float* hp = &H[n * 32 + h * 8];
    int b = lBase + h * 8;
    float a0 = 0.f, a1 = 0.f, a2 = 0.f, a3 = 0.f;
#pragma unroll
    for (int d = 0; d < 8; d++) {
        float x = hp[d];
        a0 += x * ldf(attS, b + d, f32);         // att_src[l][0]
        a1 += x * ldf(attD, b + 32 + d, f32);    // att_dst[l][1]
        a2 += x * ldf(attS, b + 64 + d, f32);    // att_src[l][2]
        a3 += x * ldf(attD, b + 64 + d, f32);    // att_dst[l][2]
    }
    as0[idx] = a0; ad1[idx] = a1; as2[idx] = a2; ad2[idx] = a3;
}

// ---------- tx nodes: ad0, as1 ----------
__global__ void k_alpha_tx(const float* __restrict__ H,
                           const void* __restrict__ attS, const void* __restrict__ attD,
                           int lBase, float* __restrict__ ad0, float* __restrict__ as1,
                           const int* __restrict__ flagp) {
    int idx = blockIdx.x * blockDim.x + threadIdx.x;
    if (idx >= NT * 4) return;
    int f32 = *flagp;
    int n = idx >> 2, h = idx & 3;
    const float* hp = &H[n * 32 + h * 8];
    int b = lBase + h * 8;
    float a0 = 0.f, a1 = 0.f;
#pragma unroll
    for (int d = 0; d < 8; d++) {
        float x = hp[d];
        a0 += x * ldf(attD, b + d, f32);         // att_dst[l][0]
        a1 += x * ldf(attS, b + 32 + d, f32);    // att_src[l][1]
    }
    ad0[idx] = a0; as1[idx] = a1;
}

// ================= CSR build =================
__global__ void k_hist(const int* __restrict__ dst, int E, int* __restrict__ deg) {
    int e = blockIdx.x * blockDim.x + threadIdx.x;
    if (e < E) atomicAdd(&deg[dst[e]], 1);
}

__global__ void k_scan1(const int* __restrict__ deg, int N, int* __restrict__ bsum) {
    __shared__ int sh[256];
    int b = blockIdx.x, t = threadIdx.x;
    int i0 = b * 1024 + t * 4, s = 0;
#pragma unroll
    for (int k = 0; k < 4; k++) { int i = i0 + k; if (i < N) s += deg[i]; }
    sh[t] = s; __syncthreads();
    for (int o = 128; o > 0; o >>= 1) { if (t < o) sh[t] += sh[t + o]; __syncthreads(); }
    if (t == 0) bsum[b] = sh[0];
}

__global__ void k_scan2(int* __restrict__ bsum, int nb, int* __restrict__ off, int N) {
    __shared__ int sh[256];
    int t = threadIdx.x;
    sh[t] = (t < nb) ? bsum[t] : 0;
    __syncthreads();
    for (int o = 1; o < 256; o <<= 1) {
        int v = (t >= o) ? sh[t - o] : 0;
        __syncthreads();
        sh[t] += v;
        __syncthreads();
    }
    if (t < nb) bsum[t] = (t == 0) ? 0 : sh[t - 1];
    if (t == 0) off[N] = sh[255];
}

// in-place: reads deg from `off`, writes exclusive-scanned offsets to `off` and `cur`
__global__ void k_scan3(int* __restrict__ off, int N, const int* __restrict__ bsum,
                        int* __restrict__ cur) {
    __shared__ int sh[256];
    int b = blockIdx.x, t = threadIdx.x;
    int i0 = b * 1024 + t * 4;
    int d0 = 0, d1 = 0, d2 = 0, d3 = 0;
    if (i0 < N)     d0 = off[i0];
    if (i0 + 1 < N) d1 = off[i0 + 1];
    if (i0 + 2 < N) d2 = off[i0 + 2];
    if (i0 + 3 < N) d3 = off[i0 + 3];
    sh[t] = d0 + d1 + d2 + d3;
    __syncthreads();
    for (int o = 1; o < 256; o <<= 1) {
        int v = (t >= o) ? sh[t - o] : 0;
        __syncthreads();
        sh[t] += v;
        __syncthreads();
    }
    int run = bsum[b] + ((t == 0) ? 0 : sh[t - 1]);
    if (i0 < N)     { off[i0] = run;     cur[i0] = run;     run += d0; }
    if (i0 + 1 < N) { off[i0 + 1] = run; cur[i0 + 1] = run; run += d1; }
    if (i0 + 2 < N) { off[i0 + 2] = run; cur[i0 + 2] = run; run += d2; }
    if (i0 + 3 < N) { off[i0 + 3] = run; cur[i0 + 3] = run; run += d3; }
}

__global__ void k_scatter(const int* __restrict__ src, const int* __restrict__ dst, int E,
                          int* __restrict__ cur, int* __restrict__ csr) {
    int e = blockIdx.x * blockDim.x + threadIdx.x;
    if (e >= E) return;
    int pos = atomicAdd(&cur[dst[e]], 1);
    csr[pos] = src[e];
}

// ========== relation gather: 32 lanes per dst, fused softmax-normalize + relu ==========
__global__ void k_gather(const int* __restrict__ off, const int* __restrict__ csr,
                         const float* __restrict__ as_, const float* __restrict__ ad_,
                         const float* __restrict__ Hs, float* __restrict__ O, int Nd) {
    int tid = blockIdx.x * blockDim.x + threadIdx.x;
    int n = tid >> 5;
    if (n >= Nd) return;
    int j = tid & 31, h = j >> 3;
    float ad = ad_[n * 4 + h];
    int p0 = off[n], p1 = off[n + 1];
    float acc = 0.f, se = 0.f;
    for (int p = p0; p < p1; p++) {
        int s = csr[p];
        float l = as_[s * 4 + h] + ad;
        l = (l >= 0.f) ? l : 0.2f * l;
        float ev = __expf(l);
        se += ev;
        acc += ev * Hs[s * 32 + j];
    }
    float v = acc / (se + 1e-16f);
    O[n * 32 + j] = (v > 0.f) ? v : 0.f;
}

// ---------- semantic reduce ----------
__global__ void k_sem_reduce(const float* __restrict__ O, int N,
                             const void* __restrict__ kWp, int kwOff,
                             const void* __restrict__ kbp, int kbOff,
                             float* __restrict__ accum, const int* __restrict__ flagp) {
    int f32 = *flagp;
    __shared__ float w[1056];
    __shared__ float sacc[32];
    for (int i = threadIdx.x; i < 1024; i += blockDim.x) w[i] = ldf(kWp, kwOff + i, f32);
    if (threadIdx.x < 32) {
        w[1024 + threadIdx.x] = ldf(kbp, kbOff + threadIdx.x, f32);
        sacc[threadIdx.x] = 0.f;
    }
    __syncthreads();
    int n = blockIdx.x * blockDim.x + threadIdx.x;
    float y[32];
    if (n < N) {
        float x[32];
#pragma unroll
        for (int k = 0; k < 32; k++) x[k] = O[(long)n * 32 + k];
#pragma unroll
        for (int f = 0; f < 32; f++) {
            float acc = w[1024 + f];
#pragma unroll
            for (int k = 0; k < 32; k++) acc += x[k] * w[k * 32 + f];
            y[f] = tanhf(acc);
        }
    } else {
#pragma unroll
        for (int f = 0; f < 32; f++) y[f] = 0.f;
    }
#pragma unroll
    for (int f = 0; f < 32; f++) {
        float v = y[f];
        for (int o = 32; o > 0; o >>= 1) v += __shfl_xor(v, o, 64);
        if ((threadIdx.x & 63) == 0) atomicAdd(&sacc[f], v);
    }
    __syncthreads();
    if (threadIdx.x < 32) atomicAdd(&accum[threadIdx.x], sacc[threadIdx.x]);
}

__global__ void k_sem_attn(const float* __restrict__ accum, float Ninv,
                           const void* __restrict__ q, int qOff,
                           float* __restrict__ attn, const int* __restrict__ flagp) {
    if (threadIdx.x == 0) {
        int f32 = *flagp;
        float s0 = 0.f, s1 = 0.f;
        for (int f = 0; f < 32; f++) {
            float qf = ldf(q, qOff + f, f32);
            s0 += accum[f] * Ninv * qf;
            s1 += accum[32 + f] * Ninv * qf;
        }
        float m = fmaxf(s0, s1);
        float e0 = __expf(s0 - m), e1 = __expf(s1 - m);
        float inv = 1.f / (e0 + e1);
        attn[0] = e0 * inv;
        attn[1] = e1 * inv;
    }
}

__global__ void k_combine(const float* __restrict__ o1, const float* __restrict__ o2,
                          const float* __restrict__ attn, float* __restrict__ out, int N) {
    int idx = blockIdx.x * blockDim.x + threadIdx.x;
    if (idx >= N * 32) return;
    float v = attn[0] * o1[idx] + attn[1] * o2[idx];
    out[idx] = (v > 0.f) ? v : 0.f;
}

__global__ void k_final(const float* __restrict__ A,
                        const void* __restrict__ linW, const void* __restrict__ linb,
                        void* __restrict__ out, int N, const int* __restrict__ flagp) {
    int idx = blockIdx.x * blockDim.x + threadIdx.x;
    if (idx >= N * 2) return;
    int f32 = *flagp;
    int n = idx >> 1, c = idx & 1;
    float acc = ldf(linb, c, f32);
    for (int f = 0; f < 32; f++) acc += A[(long)n * 32 + f] * ldf(linW, f * 2 + c, f32);
    if (f32) ((float*)out)[idx] = acc;
    else ((__hip_bfloat16*)out)[idx] = __float2bfloat16(acc);
}

static inline int gblocks(long n) { return (int)((n + 255) / 256); }

static void build_csr(const int* src, const int* dst, int E, int Nd,
                      int* off, int* cur, int* bsum, int* csr, hipStream_t stream) {
    (void)hipMemsetAsync(off, 0, (size_t)(Nd + 1) * sizeof(int), stream);
    k_hist<<<gblocks(E), 256, 0, stream>>>(dst, E, off);
    int nb = (Nd + 1023) / 1024;
    k_scan1<<<nb, 256, 0, stream>>>(off, Nd, bsum);
    k_scan2<<<1, 256, 0, stream>>>(bsum, nb, off, Nd);
    k_scan3<<<nb, 256, 0, stream>>>(off, Nd, bsum, cur);
    k_scatter<<<gblocks(E), 256, 0, stream>>>(src, dst, E, cur, csr);
}

extern "C" void kernel_launch(void* const* d_in, const int* in_sizes, int n_in,
                              void* d_out, int out_size, void* d_ws, size_t ws_size,
                              hipStream_t stream) {
    const void* x_addr = d_in[0];
    const void* x_tx   = d_in[1];
    const int* eat_s = (const int*)d_in[2];
    const int* eat_d = (const int*)d_in[3];
    const int* eta_s = (const int*)d_in[4];
    const int* eta_d = (const int*)d_in[5];
    const int* eaa_s = (const int*)d_in[6];
    const int* eaa_d = (const int*)d_in[7];
    const void* pW1  = d_in[8];
    const void* pb1  = d_in[9];
    const void* pW23 = d_in[10];
    const void* pb23 = d_in[11];
    const void* attS = d_in[12];
    const void* attD = d_in[13];
    const void* kW   = d_in[14];
    const void* kb   = d_in[15];
    const void* qv   = d_in[16];
    const void* linW = d_in[17];
    const void* linb = d_in[18];

    const size_t NA32 = (size_t)NA * 32, NT32 = (size_t)NT * 32;
    const size_t NA4 = (size_t)NA * 4, NT4 = (size_t)NT * 4;

    float* ws    = (float*)d_ws;
    float* abufA = ws;                  // a_cur ping
    float* abufB = abufA + NA32;        // a_cur pong
    float* h_a   = abufB + NA32;
    float* h_t   = h_a + NA32;
    float* o_a1  = h_t + NT32;
    float* o_a2  = o_a1 + NA32;
    float* o_tx  = o_a2 + NA32;
    float* as0   = o_tx + NT32;
    float* ad1   = as0 + NA4;
    float* as2   = ad1 + NA4;
    float* ad2   = as2 + NA4;
    float* as1   = ad2 + NA4;
    float* ad0   = as1 + NT4;
    float* sem   = ad0 + NT4;           // 64 accum + 2 attn
    int*   flagp = (int*)(sem + 66);
    int*   off_at = flagp + 16;         // NT+1
    int*   off_ta = off_at + (NT + 1);  // NA+1
    int*   off_aa = off_ta + (NA + 1);  // NA+1
    int*   csr_at = off_aa + (NA + 1);  // E_AT
    int*   csr_ta = csr_at + E_AT;      // E_TA
    int*   csr_aa = csr_ta + E_TA;      // E_AA
    int*   cur    = csr_aa + E_AA;      // max(NT,NA)+1 shared scratch
    int*   bsum   = cur + (NT + 1);     // 512

    k_detect<<<1, 256, 0, stream>>>(x_addr, flagp);

    // CSR once per call (edge lists are layer-invariant)
    build_csr(eat_s, eat_d, E_AT, NT, off_at, cur, bsum, csr_at, stream);
    build_csr(eta_s, eta_d, E_TA, NA, off_ta, cur, bsum, csr_ta, stream);
    build_csr(eaa_s, eaa_d, E_AA, NA, off_aa, cur, bsum, csr_aa, stream);

    float* a_cur = nullptr;
    float* t_cur = nullptr;

    for (int l = 0; l < 3; l++) {
        // projections (read a_cur/t_cur from previous layer; o_tx is reused as t_cur,
        // but proj completes before gather overwrites it — stream-ordered)
        if (l == 0) {
            k_proj<<<gblocks(NA32), 256, 0, stream>>>(x_addr, 0, pW1, 0,    pb1, 0,  h_a, NA, 64, flagp);
            k_proj<<<gblocks(NT32), 256, 0, stream>>>(x_tx,   0, pW1, 2048, pb1, 32, h_t, NT, 64, flagp);
        } else {
            int wi = (l - 1) * 2;
            k_proj<<<gblocks(NA32), 256, 0, stream>>>(a_cur, 1, pW23, (wi + 0) * 1024, pb23, (wi + 0) * 32, h_a, NA, 32, flagp);
            k_proj<<<gblocks(NT32), 256, 0, stream>>>(t_cur, 1, pW23, (wi + 1) * 1024, pb23, (wi + 1) * 32, h_t, NT, 32, flagp);
        }
        // attention coefficients (2 fused dispatches)
        k_alpha_addr<<<gblocks(NA4), 256, 0, stream>>>(h_a, attS, attD, l * 96, as0, ad1, as2, ad2, flagp);
        k_alpha_tx<<<gblocks(NT4), 256, 0, stream>>>(h_t, attS, attD, l * 96, ad0, as1, flagp);
        // relation gathers (no atomics, fused normalize+relu, outputs fully overwritten)
        k_gather<<<gblocks((long)NT * 32), 256, 0, stream>>>(off_at, csr_at, as0, ad0, h_a, o_tx, NT);
        k_gather<<<gblocks((long)NA * 32), 256, 0, stream>>>(off_ta, csr_ta, as1, ad1, h_t, o_a1, NA);
        k_gather<<<gblocks((long)NA * 32), 256, 0, stream>>>(off_aa, csr_aa, as2, ad2, h_a, o_a2, NA);
        // semantic attention over {o_a1, o_a2}; tx side is identity (R=1)
        (void)hipMemsetAsync(sem, 0, 66 * sizeof(float), stream);
        k_sem_reduce<<<gblocks(NA), 256, 0, stream>>>(o_a1, NA, kW, l * 1024, kb, l * 32, sem,      flagp);
        k_sem_reduce<<<gblocks(NA), 256, 0, stream>>>(o_a2, NA, kW, l * 1024, kb, l * 32, sem + 32, flagp);
        k_sem_attn<<<1, 64, 0, stream>>>(sem, 1.0f / NA, qv, l * 32, sem + 64, flagp);
        float* a_next = (l & 1) ? abufB : abufA;
        k_combine<<<gblocks(NA32), 256, 0, stream>>>(o_a1, o_a2, sem + 64, a_next, NA);
        a_cur = a_next;
        t_cur = o_tx;
    }
    k_final<<<gblocks((long)NA * 2), 256, 0, stream>>>(a_cur, linW, linb, d_out, NA, flagp);
}

// Round 3
// 1434.719 us; speedup vs baseline: 5.6222x; 1.4092x over previous
//
#include <hip/hip_runtime.h>
#include <hip/hip_bf16.h>

#define NA 150000
#define NT 200000
#define E_AT 1000000
#define E_TA 1000000
#define E_AA 500000

// ---------- dtype-flexible load: flag==1 -> fp32, flag==0 -> bf16 ----------
__device__ __forceinline__ float ldf(const void* p, long i, int f32) {
    if (f32) return ((const float*)p)[i];
    unsigned int u = ((const unsigned short*)p)[i];
    union { unsigned int ui; float f; } v; v.ui = u << 16;
    return v.f;
}
__device__ __forceinline__ float bf2f(unsigned short u) {
    union { unsigned int ui; float f; } v; v.ui = ((unsigned int)u) << 16;
    return v.f;
}

// ---------- detect fp32 (1) vs bf16 (0) float inputs ----------
__global__ void k_detect(const void* __restrict__ x, int* __restrict__ flag) {
    __shared__ int cnt;
    if (threadIdx.x == 0) cnt = 0;
    __syncthreads();
    const unsigned short* u = (const unsigned short*)x;
    int wild = 0;
    for (int i = threadIdx.x; i < 4096; i += 256) {
        unsigned short v = u[i];
        int e = (v >> 7) & 0xFF;
        if (e > 133 || (e != 0 && e < 100)) wild++;
        else if (e == 0 && (v & 0x7F)) wild++;
    }
    atomicAdd(&cnt, wild);
    __syncthreads();
    if (threadIdx.x == 0) *flag = (cnt > 1024) ? 1 : 0;
}

// ========== fused projection + per-head attention dots ==========
// Block: 256 threads = 64 nodes x 4 heads. Thread owns 8 output cols (its head).
// H[n,32] = X[n,:K] @ W[K,32] + B ; then alpha dots vs att vectors.
// att layout: [layer, edge_type, H=4, D=8] -> lBase + e*32 + h*8 + d
template<int K, bool ISADDR, bool ISFIRST>
__global__ __launch_bounds__(256) void k_proj_fused(
        const void* __restrict__ X,
        const void* __restrict__ W, int wOff,
        const void* __restrict__ B, int bOff,
        float* __restrict__ H, int N,
        const void* __restrict__ attS, const void* __restrict__ attD, int lBase,
        float* __restrict__ a0p, float* __restrict__ a1p,
        float* __restrict__ a2p, float* __restrict__ a3p,
        const int* __restrict__ flagp) {
    constexpr int XS = K + 4;                     // padded row stride (16B-aligned)
    __shared__ float Ws[K * 32];
    __shared__ float Xs[64 * XS];
    const int f32 = *flagp;
    const int t = threadIdx.x;
    // stage W tile
    for (int i = t; i < K * 32; i += 256) Ws[i] = ldf(W, wOff + i, f32);
    // stage X tile (64 rows), dtype branch hoisted out of the loop
    const long n0 = (long)blockIdx.x * 64;
    constexpr int TOT4 = 64 * K / 4;
    if (!ISFIRST || f32) {
        const float* Xf = (const float*)X;
        for (int i = t; i < TOT4; i += 256) {
            int g = i * 4;
            int r = g / K, c = g & (K - 1);
            long gr = n0 + r; if (gr >= N) gr = N - 1;
            float4 v = *(const float4*)&Xf[gr * K + c];
            float* dst = &Xs[r * XS + c];
            dst[0] = v.x; dst[1] = v.y; dst[2] = v.z; dst[3] = v.w;
        }
    } else {
        const unsigned short* Xh = (const unsigned short*)X;
        for (int i = t; i < TOT4; i += 256) {
            int g = i * 4;
            int r = g / K, c = g & (K - 1);
            long gr = n0 + r; if (gr >= N) gr = N - 1;
            ushort4 v = *(const ushort4*)&Xh[gr * K + c];
            float* dst = &Xs[r * XS + c];
            dst[0] = bf2f(v.x); dst[1] = bf2f(v.y); dst[2] = bf2f(v.z); dst[3] = bf2f(v.w);
        }
    }
    __syncthreads();
    const int nl = t >> 2, cg = t & 3;
    const long n = n0 + nl;
    float acc[8];
#pragma unroll
    for (int j = 0; j < 8; j++) acc[j] = ldf(B, bOff + cg * 8 + j, f32);
#pragma unroll
    for (int k = 0; k < K; k += 4) {
        float4 xv = *(const float4*)&Xs[nl * XS + k];
        const float x0 = xv.x, x1 = xv.y, x2 = xv.z, x3 = xv.w;
        const float* w0 = &Ws[(k + 0) * 32 + cg * 8];
        const float* w1 = &Ws[(k + 1) * 32 + cg * 8];
        const float* w2 = &Ws[(k + 2) * 32 + cg * 8];
        const float* w3 = &Ws[(k + 3) * 32 + cg * 8];
#pragma unroll
        for (int j = 0; j < 8; j++)
            acc[j] += x0 * w0[j] + x1 * w1[j] + x2 * w2[j] + x3 * w3[j];
    }
    if (n < N) {
        float* hp = &H[n * 32 + cg * 8];
        *(float4*)hp       = make_float4(acc[0], acc[1], acc[2], acc[3]);
        *(float4*)(hp + 4) = make_float4(acc[4], acc[5], acc[6], acc[7]);
        // alpha dots for head h = cg
        const int b = lBase + cg * 8;
        float d0 = 0.f, d1 = 0.f, d2 = 0.f, d3 = 0.f;
#pragma unroll
        for (int d = 0; d < 8; d++) {
            float x = acc[d];
            if (ISADDR) {
                d0 += x * ldf(attS, b + d, f32);        // att_src[l][0]
                d1 += x * ldf(attD, b + 32 + d, f32);   // att_dst[l][1]
                d2 += x * ldf(attS, b + 64 + d, f32);   // att_src[l][2]
                d3 += x * ldf(attD, b + 64 + d, f32);   // att_dst[l][2]
            } else {
                d0 += x * ldf(attD, b + d, f32);        // att_dst[l][0]
                d1 += x * ldf(attS, b + 32 + d, f32);   // att_src[l][1]
            }
        }
        a0p[n * 4 + cg] = d0;
        a1p[n * 4 + cg] = d1;
        if (ISADDR) { a2p[n * 4 + cg] = d2; a3p[n * 4 + cg] = d3; }
    }
}

// ================= CSR build =================
__global__ void k_hist(const int* __restrict__ dst, int E, int* __restrict__ deg) {
    int e = blockIdx.x * blockDim.x + threadIdx.x;
    if (e < E) atomicAdd(&deg[dst[e]], 1);
}

__global__ void k_scan1(const int* __restrict__ deg, int N, int* __restrict__ bsum) {
    __shared__ int sh[256];
    int b = blockIdx.x, t = threadIdx.x;
    int i0 = b * 1024 + t * 4, s = 0;
#pragma unroll
    for (int k = 0; k < 4; k++) { int i = i0 + k; if (i < N) s += deg[i]; }
    sh[t] = s; __syncthreads();
    for (int o = 128; o > 0; o >>= 1) { if (t < o) sh[t] += sh[t + o]; __syncthreads(); }
    if (t == 0) bsum[b] = sh[0];
}

__global__ void k_scan2(int* __restrict__ bsum, int nb, int* __restrict__ off, int N) {
    __shared__ int sh[256];
    int t = threadIdx.x;
    sh[t] = (t < nb) ? bsum[t] : 0;
    __syncthreads();
    for (int o = 1; o < 256; o <<= 1) {
        int v = (t >= o) ? sh[t - o] : 0;
        __syncthreads();
        sh[t] += v;
        __syncthreads();
    }
    if (t < nb) bsum[t] = (t == 0) ? 0 : sh[t - 1];
    if (t == 0) off[N] = sh[255];
}

__global__ void k_scan3(int* __restrict__ off, int N, const int* __restrict__ bsum,
                        int* __restrict__ cur) {
    __shared__ int sh[256];
    int b = blockIdx.x, t = threadIdx.x;
    int i0 = b * 1024 + t * 4;
    int d0 = 0, d1 = 0, d2 = 0, d3 = 0;
    if (i0 < N)     d0 = off[i0];
    if (i0 + 1 < N) d1 = off[i0 + 1];
    if (i0 + 2 < N) d2 = off[i0 + 2];
    if (i0 + 3 < N) d3 = off[i0 + 3];
    sh[t] = d0 + d1 + d2 + d3;
    __syncthreads();
    for (int o = 1; o < 256; o <<= 1) {
        int v = (t >= o) ? sh[t - o] : 0;
        __syncthreads();
        sh[t] += v;
        __syncthreads();
    }
    int run = bsum[b] + ((t == 0) ? 0 : sh[t - 1]);
    if (i0 < N)     { off[i0] = run;     cur[i0] = run;     run += d0; }
    if (i0 + 1 < N) { off[i0 + 1] = run; cur[i0 + 1] = run; run += d1; }
    if (i0 + 2 < N) { off[i0 + 2] = run; cur[i0 + 2] = run; run += d2; }
    if (i0 + 3 < N) { off[i0 + 3] = run; cur[i0 + 3] = run; run += d3; }
}

__global__ void k_scatter(const int* __restrict__ src, const int* __restrict__ dst, int E,
                          int* __restrict__ cur, int* __restrict__ csr) {
    int e = blockIdx.x * blockDim.x + threadIdx.x;
    if (e >= E) return;
    int pos = atomicAdd(&cur[dst[e]], 1);
    csr[pos] = src[e];
}

// ========== relation gather: 32 lanes per dst, fused softmax-normalize + relu ==========
__global__ void k_gather(const int* __restrict__ off, const int* __restrict__ csr,
                         const float* __restrict__ as_, const float* __restrict__ ad_,
                         const float* __restrict__ Hs, float* __restrict__ O, int Nd) {
    int tid = blockIdx.x * blockDim.x + threadIdx.x;
    int n = tid >> 5;
    if (n >= Nd) return;
    int j = tid & 31, h = j >> 3;
    float ad = ad_[n * 4 + h];
    int p0 = off[n], p1 = off[n + 1];
    float acc = 0.f, se = 0.f;
    for (int p = p0; p < p1; p++) {
        int s = csr[p];
        float l = as_[s * 4 + h] + ad;
        l = (l >= 0.f) ? l : 0.2f * l;
        float ev = __expf(l);
        se += ev;
        acc += ev * Hs[s * 32 + j];
    }
    float v = acc / (se + 1e-16f);
    O[n * 32 + j] = (v > 0.f) ? v : 0.f;
}

// ---------- semantic reduce ----------
__global__ void k_sem_reduce(const float* __restrict__ O, int N,
                             const void* __restrict__ kWp, int kwOff,
                             const void* __restrict__ kbp, int kbOff,
                             float* __restrict__ accum, const int* __restrict__ flagp) {
    int f32 = *flagp;
    __shared__ float w[1056];
    __shared__ float sacc[32];
    for (int i = threadIdx.x; i < 1024; i += blockDim.x) w[i] = ldf(kWp, kwOff + i, f32);
    if (threadIdx.x < 32) {
        w[1024 + threadIdx.x] = ldf(kbp, kbOff + threadIdx.x, f32);
        sacc[threadIdx.x] = 0.f;
    }
    __syncthreads();
    int n = blockIdx.x * blockDim.x + threadIdx.x;
    float y[32];
    if (n < N) {
        float x[32];
#pragma unroll
        for (int k = 0; k < 32; k++) x[k] = O[(long)n * 32 + k];
#pragma unroll
        for (int f = 0; f < 32; f++) {
            float acc = w[1024 + f];
#pragma unroll
            for (int k = 0; k < 32; k++) acc += x[k] * w[k * 32 + f];
            y[f] = tanhf(acc);
        }
    } else {
#pragma unroll
        for (int f = 0; f < 32; f++) y[f] = 0.f;
    }
#pragma unroll
    for (int f = 0; f < 32; f++) {
        float v = y[f];
        for (int o = 32; o > 0; o >>= 1) v += __shfl_xor(v, o, 64);
        if ((threadIdx.x & 63) == 0) atomicAdd(&sacc[f], v);
    }
    __syncthreads();
    if (threadIdx.x < 32) atomicAdd(&accum[threadIdx.x], sacc[threadIdx.x]);
}

__global__ void k_sem_attn(const float* __restrict__ accum, float Ninv,
                           const void* __restrict__ q, int qOff,
                           float* __restrict__ attn, const int* __restrict__ flagp) {
    if (threadIdx.x == 0) {
        int f32 = *flagp;
        float s0 = 0.f, s1 = 0.f;
        for (int f = 0; f < 32; f++) {
            float qf = ldf(q, qOff + f, f32);
            s0 += accum[f] * Ninv * qf;
            s1 += accum[32 + f] * Ninv * qf;
        }
        float m = fmaxf(s0, s1);
        float e0 = __expf(s0 - m), e1 = __expf(s1 - m);
        float inv = 1.f / (e0 + e1);
        attn[0] = e0 * inv;
        attn[1] = e1 * inv;
    }
}

__global__ void k_combine(const float* __restrict__ o1, const float* __restrict__ o2,
                          const float* __restrict__ attn, float* __restrict__ out, int N) {
    int idx = blockIdx.x * blockDim.x + threadIdx.x;
    if (idx >= N * 32) return;
    float v = attn[0] * o1[idx] + attn[1] * o2[idx];
    out[idx] = (v > 0.f) ? v : 0.f;
}

// ---------- fused combine + final linear (layer 3 only) ----------
__global__ void k_combine_final(const float* __restrict__ o1, const float* __restrict__ o2,
                                const float* __restrict__ attn,
                                const void* __restrict__ linW, const void* __restrict__ linb,
                                void* __restrict__ out, int N, const int* __restrict__ flagp) {
    int n = blockIdx.x * blockDim.x + threadIdx.x;
    if (n >= N) return;
    int f32 = *flagp;
    float w0 = attn[0], w1 = attn[1];
    float s0 = ldf(linb, 0, f32), s1 = ldf(linb, 1, f32);
    const float* p1 = &o1[(long)n * 32];
    const float* p2 = &o2[(long)n * 32];
#pragma unroll
    for (int f = 0; f < 32; f++) {
        float v = w0 * p1[f] + w1 * p2[f];
        v = (v > 0.f) ? v : 0.f;
        s0 += v * ldf(linW, f * 2, f32);
        s1 += v * ldf(linW, f * 2 + 1, f32);
    }
    if (f32) { ((float*)out)[n * 2] = s0; ((float*)out)[n * 2 + 1] = s1; }
    else {
        ((__hip_bfloat16*)out)[n * 2] = __float2bfloat16(s0);
        ((__hip_bfloat16*)out)[n * 2 + 1] = __float2bfloat16(s1);
    }
}

static inline int gblocks(long n) { return (int)((n + 255) / 256); }

static void build_csr(const int* src, const int* dst, int E, int Nd,
                      int* off, int* cur, int* bsum, int* csr, hipStream_t stream) {
    (void)hipMemsetAsync(off, 0, (size_t)(Nd + 1) * sizeof(int), stream);
    k_hist<<<gblocks(E), 256, 0, stream>>>(dst, E, off);
    int nb = (Nd + 1023) / 1024;
    k_scan1<<<nb, 256, 0, stream>>>(off, Nd, bsum);
    k_scan2<<<1, 256, 0, stream>>>(bsum, nb, off, Nd);
    k_scan3<<<nb, 256, 0, stream>>>(off, Nd, bsum, cur);
    k_scatter<<<gblocks(E), 256, 0, stream>>>(src, dst, E, cur, csr);
}

extern "C" void kernel_launch(void* const* d_in, const int* in_sizes, int n_in,
                              void* d_out, int out_size, void* d_ws, size_t ws_size,
                              hipStream_t stream) {
    const void* x_addr = d_in[0];
    const void* x_tx   = d_in[1];
    const int* eat_s = (const int*)d_in[2];
    const int* eat_d = (const int*)d_in[3];
    const int* eta_s = (const int*)d_in[4];
    const int* eta_d = (const int*)d_in[5];
    const int* eaa_s = (const int*)d_in[6];
    const int* eaa_d = (const int*)d_in[7];
    const void* pW1  = d_in[8];
    const void* pb1  = d_in[9];
    const void* pW23 = d_in[10];
    const void* pb23 = d_in[11];
    const void* attS = d_in[12];
    const void* attD = d_in[13];
    const void* kW   = d_in[14];
    const void* kb   = d_in[15];
    const void* qv   = d_in[16];
    const void* linW = d_in[17];
    const void* linb = d_in[18];

    const size_t NA32 = (size_t)NA * 32, NT32 = (size_t)NT * 32;
    const size_t NA4 = (size_t)NA * 4, NT4 = (size_t)NT * 4;

    float* ws    = (float*)d_ws;
    float* abufA = ws;
    float* abufB = abufA + NA32;
    float* h_a   = abufB + NA32;
    float* h_t   = h_a + NA32;
    float* o_a1  = h_t + NT32;
    float* o_a2  = o_a1 + NA32;
    float* o_tx  = o_a2 + NA32;
    float* as0   = o_tx + NT32;
    float* ad1   = as0 + NA4;
    float* as2   = ad1 + NA4;
    float* ad2   = as2 + NA4;
    float* as1   = ad2 + NA4;
    float* ad0   = as1 + NT4;
    float* sem   = ad0 + NT4;
    int*   flagp = (int*)(sem + 66);
    int*   off_at = flagp + 16;
    int*   off_ta = off_at + (NT + 1);
    int*   off_aa = off_ta + (NA + 1);
    int*   csr_at = off_aa + (NA + 1);
    int*   csr_ta = csr_at + E_AT;
    int*   csr_aa = csr_ta + E_TA;
    int*   cur    = csr_aa + E_AA;
    int*   bsum   = cur + (NT + 1);

    k_detect<<<1, 256, 0, stream>>>(x_addr, flagp);

    build_csr(eat_s, eat_d, E_AT, NT, off_at, cur, bsum, csr_at, stream);
    build_csr(eta_s, eta_d, E_TA, NA, off_ta, cur, bsum, csr_ta, stream);
    build_csr(eaa_s, eaa_d, E_AA, NA, off_aa, cur, bsum, csr_aa, stream);

    float* a_cur = nullptr;
    float* t_cur = nullptr;
    const int gA = (NA + 63) / 64, gT = (NT + 63) / 64;

    for (int l = 0; l < 3; l++) {
        if (l == 0) {
            k_proj_fused<64, true, true><<<gA, 256, 0, stream>>>(
                x_addr, pW1, 0, pb1, 0, h_a, NA, attS, attD, 0,
                as0, ad1, as2, ad2, flagp);
            k_proj_fused<64, false, true><<<gT, 256, 0, stream>>>(
                x_tx, pW1, 2048, pb1, 32, h_t, NT, attS, attD, 0,
                ad0, as1, nullptr, nullptr, flagp);
        } else {
            int wi = (l - 1) * 2;
            k_proj_fused<32, true, false><<<gA, 256, 0, stream>>>(
                a_cur, pW23, (wi + 0) * 1024, pb23, (wi + 0) * 32, h_a, NA, attS, attD, l * 96,
                as0, ad1, as2, ad2, flagp);
            k_proj_fused<32, false, false><<<gT, 256, 0, stream>>>(
                t_cur, pW23, (wi + 1) * 1024, pb23, (wi + 1) * 32, h_t, NT, attS, attD, l * 96,
                ad0, as1, nullptr, nullptr, flagp);
        }
        // relation gathers
        k_gather<<<gblocks((long)NT * 32), 256, 0, stream>>>(off_at, csr_at, as0, ad0, h_a, o_tx, NT);
        k_gather<<<gblocks((long)NA * 32), 256, 0, stream>>>(off_ta, csr_ta, as1, ad1, h_t, o_a1, NA);
        k_gather<<<gblocks((long)NA * 32), 256, 0, stream>>>(off_aa, csr_aa, as2, ad2, h_a, o_a2, NA);
        // semantic attention over {o_a1, o_a2}; tx side identity (R=1)
        (void)hipMemsetAsync(sem, 0, 66 * sizeof(float), stream);
        k_sem_reduce<<<gblocks(NA), 256, 0, stream>>>(o_a1, NA, kW, l * 1024, kb, l * 32, sem,      flagp);
        k_sem_reduce<<<gblocks(NA), 256, 0, stream>>>(o_a2, NA, kW, l * 1024, kb, l * 32, sem + 32, flagp);
        k_sem_attn<<<1, 64, 0, stream>>>(sem, 1.0f / NA, qv, l * 32, sem + 64, flagp);
        if (l < 2) {
            float* a_next = (l & 1) ? abufB : abufA;
            k_combine<<<gblocks(NA32), 256, 0, stream>>>(o_a1, o_a2, sem + 64, a_next, NA);
            a_cur = a_next;
        } else {
            k_combine_final<<<gblocks(NA), 256, 0, stream>>>(o_a1, o_a2, sem + 64,
                                                             linW, linb, d_out, NA, flagp);
        }
        t_cur = o_tx;
    }
}

// Round 4
// 1144.972 us; speedup vs baseline: 7.0449x; 1.2531x over previous
//
#include <hip/hip_runtime.h>
#include <hip/hip_bf16.h>

#define NA 150000
#define NT 200000
#define E_AT 1000000
#define E_TA 1000000
#define E_AA 500000

// ---------- dtype-flexible load: flag==1 -> fp32, flag==0 -> bf16 ----------
__device__ __forceinline__ float ldf(const void* p, long i, int f32) {
    if (f32) return ((const float*)p)[i];
    unsigned int u = ((const unsigned short*)p)[i];
    union { unsigned int ui; float f; } v; v.ui = u << 16;
    return v.f;
}
__device__ __forceinline__ float bf2f(unsigned short u) {
    union { unsigned int ui; float f; } v; v.ui = ((unsigned int)u) << 16;
    return v.f;
}

// ---------- detect fp32 (1) vs bf16 (0) float inputs ----------
__global__ void k_detect(const void* __restrict__ x, int* __restrict__ flag) {
    __shared__ int cnt;
    if (threadIdx.x == 0) cnt = 0;
    __syncthreads();
    const unsigned short* u = (const unsigned short*)x;
    int wild = 0;
    for (int i = threadIdx.x; i < 4096; i += 256) {
        unsigned short v = u[i];
        int e = (v >> 7) & 0xFF;
        if (e > 133 || (e != 0 && e < 100)) wild++;
        else if (e == 0 && (v & 0x7F)) wild++;
    }
    atomicAdd(&cnt, wild);
    __syncthreads();
    if (threadIdx.x == 0) *flag = (cnt > 1024) ? 1 : 0;
}

// ========== fused projection + per-head attention dots ==========
// Block: 256 threads = 64 nodes x 4 heads. Thread owns 8 output cols (its head).
// XMODE: 0 = global input (dtype-flagged), 1 = ws fp32, 2 = combine(o1,o2,attn)+relu
template<int K, bool ISADDR, int XMODE>
__global__ __launch_bounds__(256) void k_proj_fused(
        const void* __restrict__ X, const void* __restrict__ X2,
        const float* __restrict__ attn,
        const void* __restrict__ W, int wOff,
        const void* __restrict__ B, int bOff,
        float* __restrict__ H, int N,
        const void* __restrict__ attS, const void* __restrict__ attD, int lBase,
        float* __restrict__ a0p, float* __restrict__ a1p,
        float* __restrict__ a2p, float* __restrict__ a3p,
        const int* __restrict__ flagp) {
    constexpr int XS = K + 4;
    __shared__ float Ws[K * 32];
    __shared__ float Xs[64 * XS];
    const int f32 = *flagp;
    const int t = threadIdx.x;
    for (int i = t; i < K * 32; i += 256) Ws[i] = ldf(W, wOff + i, f32);
    const long n0 = (long)blockIdx.x * 64;
    constexpr int TOT4 = 64 * K / 4;
    if (XMODE == 2) {
        const float w0 = attn[0], w1 = attn[1];
        const float* Xa = (const float*)X;
        const float* Xb = (const float*)X2;
        for (int i = t; i < TOT4; i += 256) {
            int g = i * 4;
            int r = g / K, c = g & (K - 1);
            long gr = n0 + r; if (gr >= N) gr = N - 1;
            float4 va = *(const float4*)&Xa[gr * K + c];
            float4 vb = *(const float4*)&Xb[gr * K + c];
            float* dst = &Xs[r * XS + c];
            float v0 = w0 * va.x + w1 * vb.x;
            float v1 = w0 * va.y + w1 * vb.y;
            float v2 = w0 * va.z + w1 * vb.z;
            float v3 = w0 * va.w + w1 * vb.w;
            dst[0] = (v0 > 0.f) ? v0 : 0.f;
            dst[1] = (v1 > 0.f) ? v1 : 0.f;
            dst[2] = (v2 > 0.f) ? v2 : 0.f;
            dst[3] = (v3 > 0.f) ? v3 : 0.f;
        }
    } else if (XMODE == 1 || f32) {
        const float* Xf = (const float*)X;
        for (int i = t; i < TOT4; i += 256) {
            int g = i * 4;
            int r = g / K, c = g & (K - 1);
            long gr = n0 + r; if (gr >= N) gr = N - 1;
            float4 v = *(const float4*)&Xf[gr * K + c];
            float* dst = &Xs[r * XS + c];
            dst[0] = v.x; dst[1] = v.y; dst[2] = v.z; dst[3] = v.w;
        }
    } else {
        const unsigned short* Xh = (const unsigned short*)X;
        for (int i = t; i < TOT4; i += 256) {
            int g = i * 4;
            int r = g / K, c = g & (K - 1);
            long gr = n0 + r; if (gr >= N) gr = N - 1;
            ushort4 v = *(const ushort4*)&Xh[gr * K + c];
            float* dst = &Xs[r * XS + c];
            dst[0] = bf2f(v.x); dst[1] = bf2f(v.y); dst[2] = bf2f(v.z); dst[3] = bf2f(v.w);
        }
    }
    __syncthreads();
    const int nl = t >> 2, cg = t & 3;
    const long n = n0 + nl;
    float acc[8];
#pragma unroll
    for (int j = 0; j < 8; j++) acc[j] = ldf(B, bOff + cg * 8 + j, f32);
#pragma unroll
    for (int k = 0; k < K; k += 4) {
        float4 xv = *(const float4*)&Xs[nl * XS + k];
        const float x0 = xv.x, x1 = xv.y, x2 = xv.z, x3 = xv.w;
        const float* w0 = &Ws[(k + 0) * 32 + cg * 8];
        const float* w1 = &Ws[(k + 1) * 32 + cg * 8];
        const float* w2 = &Ws[(k + 2) * 32 + cg * 8];
        const float* w3 = &Ws[(k + 3) * 32 + cg * 8];
#pragma unroll
        for (int j = 0; j < 8; j++)
            acc[j] += x0 * w0[j] + x1 * w1[j] + x2 * w2[j] + x3 * w3[j];
    }
    if (n < N) {
        float* hp = &H[n * 32 + cg * 8];
        *(float4*)hp       = make_float4(acc[0], acc[1], acc[2], acc[3]);
        *(float4*)(hp + 4) = make_float4(acc[4], acc[5], acc[6], acc[7]);
        const int b = lBase + cg * 8;
        float d0 = 0.f, d1 = 0.f, d2 = 0.f, d3 = 0.f;
#pragma unroll
        for (int d = 0; d < 8; d++) {
            float x = acc[d];
            if (ISADDR) {
                d0 += x * ldf(attS, b + d, f32);        // att_src[l][0]
                d1 += x * ldf(attD, b + 32 + d, f32);   // att_dst[l][1]
                d2 += x * ldf(attS, b + 64 + d, f32);   // att_src[l][2]
                d3 += x * ldf(attD, b + 64 + d, f32);   // att_dst[l][2]
            } else {
                d0 += x * ldf(attD, b + d, f32);        // att_dst[l][0]
                d1 += x * ldf(attS, b + 32 + d, f32);   // att_src[l][1]
            }
        }
        a0p[n * 4 + cg] = d0;
        a1p[n * 4 + cg] = d1;
        if (ISADDR) { a2p[n * 4 + cg] = d2; a3p[n * 4 + cg] = d3; }
    }
}

// ================= CSR build (3 relations fused per pass) =================
__global__ void k_hist3(const int* __restrict__ d0, const int* __restrict__ d1,
                        const int* __restrict__ d2,
                        int* __restrict__ g0, int* __restrict__ g1, int* __restrict__ g2) {
    int e = blockIdx.x * blockDim.x + threadIdx.x;
    if (e < E_AT) atomicAdd(&g0[d0[e]], 1);
    else if (e < E_AT + E_TA) atomicAdd(&g1[d1[e - E_AT]], 1);
    else if (e < E_AT + E_TA + E_AA) atomicAdd(&g2[d2[e - E_AT - E_TA]], 1);
}

__global__ void k_scan1(const int* __restrict__ deg, int N, int* __restrict__ bsum) {
    __shared__ int sh[256];
    int b = blockIdx.x, t = threadIdx.x;
    int i0 = b * 1024 + t * 4, s = 0;
#pragma unroll
    for (int k = 0; k < 4; k++) { int i = i0 + k; if (i < N) s += deg[i]; }
    sh[t] = s; __syncthreads();
    for (int o = 128; o > 0; o >>= 1) { if (t < o) sh[t] += sh[t + o]; __syncthreads(); }
    if (t == 0) bsum[b] = sh[0];
}

__global__ void k_scan2(int* __restrict__ bsum, int nb, int* __restrict__ off, int N) {
    __shared__ int sh[256];
    int t = threadIdx.x;
    sh[t] = (t < nb) ? bsum[t] : 0;
    __syncthreads();
    for (int o = 1; o < 256; o <<= 1) {
        int v = (t >= o) ? sh[t - o] : 0;
        __syncthreads();
        sh[t] += v;
        __syncthreads();
    }
    if (t < nb) bsum[t] = (t == 0) ? 0 : sh[t - 1];
    if (t == 0) off[N] = sh[255];
}

__global__ void k_scan3(int* __restrict__ off, int N, const int* __restrict__ bsum,
                        int* __restrict__ cur) {
    __shared__ int sh[256];
    int b = blockIdx.x, t = threadIdx.x;
    int i0 = b * 1024 + t * 4;
    int d0 = 0, d1 = 0, d2 = 0, d3 = 0;
    if (i0 < N)     d0 = off[i0];
    if (i0 + 1 < N) d1 = off[i0 + 1];
    if (i0 + 2 < N) d2 = off[i0 + 2];
    if (i0 + 3 < N) d3 = off[i0 + 3];
    sh[t] = d0 + d1 + d2 + d3;
    __syncthreads();
    for (int o = 1; o < 256; o <<= 1) {
        int v = (t >= o) ? sh[t - o] : 0;
        __syncthreads();
        sh[t] += v;
        __syncthreads();
    }
    int run = bsum[b] + ((t == 0) ? 0 : sh[t - 1]);
    if (i0 < N)     { off[i0] = run;     cur[i0] = run;     run += d0; }
    if (i0 + 1 < N) { off[i0 + 1] = run; cur[i0 + 1] = run; run += d1; }
    if (i0 + 2 < N) { off[i0 + 2] = run; cur[i0 + 2] = run; run += d2; }
    if (i0 + 3 < N) { off[i0 + 3] = run; cur[i0 + 3] = run; run += d3; }
}

__global__ void k_scatter3(const int* __restrict__ s0, const int* __restrict__ d0,
                           const int* __restrict__ s1, const int* __restrict__ d1,
                           const int* __restrict__ s2, const int* __restrict__ d2,
                           int* __restrict__ c0, int* __restrict__ c1, int* __restrict__ c2,
                           int* __restrict__ r0, int* __restrict__ r1, int* __restrict__ r2) {
    int e = blockIdx.x * blockDim.x + threadIdx.x;
    if (e < E_AT) { int p = atomicAdd(&c0[d0[e]], 1); r0[p] = s0[e]; }
    else if (e < E_AT + E_TA) { int i = e - E_AT; int p = atomicAdd(&c1[d1[i]], 1); r1[p] = s1[i]; }
    else if (e < E_AT + E_TA + E_AA) { int i = e - E_AT - E_TA; int p = atomicAdd(&c2[d2[i]], 1); r2[p] = s2[i]; }
}

// ========== tri-relation gather: 32 lanes/dst, 4x unrolled edge loop ==========
__global__ __launch_bounds__(256) void k_gather3(
        const int* __restrict__ off_at, const int* __restrict__ csr_at,
        const int* __restrict__ off_ta, const int* __restrict__ csr_ta,
        const int* __restrict__ off_aa, const int* __restrict__ csr_aa,
        const float* __restrict__ as0, const float* __restrict__ ad0,
        const float* __restrict__ as1, const float* __restrict__ ad1,
        const float* __restrict__ as2, const float* __restrict__ ad2,
        const float* __restrict__ h_a, const float* __restrict__ h_t,
        float* __restrict__ o_tx, float* __restrict__ o_a1, float* __restrict__ o_a2) {
    int tid = blockIdx.x * blockDim.x + threadIdx.x;
    int u = tid >> 5;
    int j = tid & 31, h = j >> 3;
    const int *off, *csr;
    const float *as_, *ad_, *Hs;
    float* O;
    int n;
    if (u < NT) {
        n = u; off = off_at; csr = csr_at; as_ = as0; ad_ = ad0; Hs = h_a; O = o_tx;
    } else if (u < NT + NA) {
        n = u - NT; off = off_ta; csr = csr_ta; as_ = as1; ad_ = ad1; Hs = h_t; O = o_a1;
    } else if (u < NT + 2 * NA) {
        n = u - NT - NA; off = off_aa; csr = csr_aa; as_ = as2; ad_ = ad2; Hs = h_a; O = o_a2;
    } else return;
    float adv = ad_[n * 4 + h];
    int p0 = off[n], p1 = off[n + 1];
    float acc = 0.f, se = 0.f;
    int p = p0;
    for (; p + 4 <= p1; p += 4) {
        int s0 = csr[p], s1 = csr[p + 1], s2 = csr[p + 2], s3 = csr[p + 3];
        float A0 = as_[s0 * 4 + h], A1 = as_[s1 * 4 + h];
        float A2 = as_[s2 * 4 + h], A3 = as_[s3 * 4 + h];
        float H0 = Hs[s0 * 32 + j], H1 = Hs[s1 * 32 + j];
        float H2 = Hs[s2 * 32 + j], H3 = Hs[s3 * 32 + j];
        float l0 = A0 + adv; l0 = (l0 >= 0.f) ? l0 : 0.2f * l0; float e0 = __expf(l0);
        float l1 = A1 + adv; l1 = (l1 >= 0.f) ? l1 : 0.2f * l1; float e1 = __expf(l1);
        float l2 = A2 + adv; l2 = (l2 >= 0.f) ? l2 : 0.2f * l2; float e2 = __expf(l2);
        float l3 = A3 + adv; l3 = (l3 >= 0.f) ? l3 : 0.2f * l3; float e3 = __expf(l3);
        se += e0 + e1 + e2 + e3;
        acc += e0 * H0 + e1 * H1 + e2 * H2 + e3 * H3;
    }
    for (; p < p1; p++) {
        int s = csr[p];
        float l = as_[s * 4 + h] + adv;
        l = (l >= 0.f) ? l : 0.2f * l;
        float ev = __expf(l);
        se += ev;
        acc += ev * Hs[s * 32 + j];
    }
    float v = acc / (se + 1e-16f);
    O[n * 32 + j] = (v > 0.f) ? v : 0.f;
}

// ---------- fused dual semantic reduce ----------
__global__ void k_sem_reduce2(const float* __restrict__ O1, const float* __restrict__ O2, int N,
                              const void* __restrict__ kWp, int kwOff,
                              const void* __restrict__ kbp, int kbOff,
                              float* __restrict__ accum, const int* __restrict__ flagp) {
    int f32 = *flagp;
    __shared__ float w[1056];
    __shared__ float sacc[64];
    for (int i = threadIdx.x; i < 1024; i += blockDim.x) w[i] = ldf(kWp, kwOff + i, f32);
    if (threadIdx.x < 32) w[1024 + threadIdx.x] = ldf(kbp, kbOff + threadIdx.x, f32);
    if (threadIdx.x < 64) sacc[threadIdx.x] = 0.f;
    __syncthreads();
    int n = blockIdx.x * blockDim.x + threadIdx.x;
    const float* Os[2] = { O1, O2 };
#pragma unroll
    for (int r = 0; r < 2; r++) {
        float y[32];
        if (n < N) {
            float x[32];
#pragma unroll
            for (int k = 0; k < 32; k++) x[k] = Os[r][(long)n * 32 + k];
#pragma unroll
            for (int f = 0; f < 32; f++) {
                float acc = w[1024 + f];
#pragma unroll
                for (int k = 0; k < 32; k++) acc += x[k] * w[k * 32 + f];
                y[f] = tanhf(acc);
            }
        } else {
#pragma unroll
            for (int f = 0; f < 32; f++) y[f] = 0.f;
        }
#pragma unroll
        for (int f = 0; f < 32; f++) {
            float v = y[f];
            for (int o = 32; o > 0; o >>= 1) v += __shfl_xor(v, o, 64);
            if ((threadIdx.x & 63) == 0) atomicAdd(&sacc[r * 32 + f], v);
        }
    }
    __syncthreads();
    if (threadIdx.x < 64) atomicAdd(&accum[threadIdx.x], sacc[threadIdx.x]);
}

__global__ void k_sem_attn(const float* __restrict__ accum, float Ninv,
                           const void* __restrict__ q, int qOff,
                           float* __restrict__ attn, const int* __restrict__ flagp) {
    if (threadIdx.x == 0) {
        int f32 = *flagp;
        float s0 = 0.f, s1 = 0.f;
        for (int f = 0; f < 32; f++) {
            float qf = ldf(q, qOff + f, f32);
            s0 += accum[f] * Ninv * qf;
            s1 += accum[32 + f] * Ninv * qf;
        }
        float m = fmaxf(s0, s1);
        float e0 = __expf(s0 - m), e1 = __expf(s1 - m);
        float inv = 1.f / (e0 + e1);
        attn[0] = e0 * inv;
        attn[1] = e1 * inv;
    }
}

// ---------- fused combine + final linear (layer 3 only) ----------
__global__ void k_combine_final(const float* __restrict__ o1, const float* __restrict__ o2,
                                const float* __restrict__ attn,
                                const void* __restrict__ linW, const void* __restrict__ linb,
                                void* __restrict__ out, int N, const int* __restrict__ flagp) {
    int n = blockIdx.x * blockDim.x + threadIdx.x;
    if (n >= N) return;
    int f32 = *flagp;
    float w0 = attn[0], w1 = attn[1];
    float s0 = ldf(linb, 0, f32), s1 = ldf(linb, 1, f32);
    const float* p1 = &o1[(long)n * 32];
    const float* p2 = &o2[(long)n * 32];
#pragma unroll
    for (int f = 0; f < 32; f++) {
        float v = w0 * p1[f] + w1 * p2[f];
        v = (v > 0.f) ? v : 0.f;
        s0 += v * ldf(linW, f * 2, f32);
        s1 += v * ldf(linW, f * 2 + 1, f32);
    }
    if (f32) { ((float*)out)[n * 2] = s0; ((float*)out)[n * 2 + 1] = s1; }
    else {
        ((__hip_bfloat16*)out)[n * 2] = __float2bfloat16(s0);
        ((__hip_bfloat16*)out)[n * 2 + 1] = __float2bfloat16(s1);
    }
}

static inline int gblocks(long n) { return (int)((n + 255) / 256); }

extern "C" void kernel_launch(void* const* d_in, const int* in_sizes, int n_in,
                              void* d_out, int out_size, void* d_ws, size_t ws_size,
                              hipStream_t stream) {
    const void* x_addr = d_in[0];
    const void* x_tx   = d_in[1];
    const int* eat_s = (const int*)d_in[2];
    const int* eat_d = (const int*)d_in[3];
    const int* eta_s = (const int*)d_in[4];
    const int* eta_d = (const int*)d_in[5];
    const int* eaa_s = (const int*)d_in[6];
    const int* eaa_d = (const int*)d_in[7];
    const void* pW1  = d_in[8];
    const void* pb1  = d_in[9];
    const void* pW23 = d_in[10];
    const void* pb23 = d_in[11];
    const void* attS = d_in[12];
    const void* attD = d_in[13];
    const void* kW   = d_in[14];
    const void* kb   = d_in[15];
    const void* qv   = d_in[16];
    const void* linW = d_in[17];
    const void* linb = d_in[18];

    const size_t NA32 = (size_t)NA * 32, NT32 = (size_t)NT * 32;
    const size_t NA4 = (size_t)NA * 4, NT4 = (size_t)NT * 4;

    float* ws    = (float*)d_ws;
    float* h_a   = ws;
    float* h_t   = h_a + NA32;
    float* o_a1  = h_t + NT32;
    float* o_a2  = o_a1 + NA32;
    float* o_tx  = o_a2 + NA32;
    float* as0   = o_tx + NT32;
    float* ad1   = as0 + NA4;
    float* as2   = ad1 + NA4;
    float* ad2   = as2 + NA4;
    float* as1   = ad2 + NA4;
    float* ad0   = as1 + NT4;
    float* sem   = ad0 + NT4;           // 64 accum + 2 attn
    int*   flagp = (int*)(sem + 66);
    int*   off_at = flagp + 16;         // NT+1, then NA+1, NA+1 (contiguous for one memset)
    int*   off_ta = off_at + (NT + 1);
    int*   off_aa = off_ta + (NA + 1);
    int*   csr_at = off_aa + (NA + 1);
    int*   csr_ta = csr_at + E_AT;
    int*   csr_aa = csr_ta + E_TA;
    int*   cur_at = csr_aa + E_AA;
    int*   cur_ta = cur_at + (NT + 1);
    int*   cur_aa = cur_ta + (NA + 1);
    int*   bsum   = cur_aa + (NA + 1);  // 512

    k_detect<<<1, 256, 0, stream>>>(x_addr, flagp);

    // ---- CSR build, 3 relations ----
    (void)hipMemsetAsync(off_at, 0, (size_t)(NT + NA + NA + 3) * sizeof(int), stream);
    k_hist3<<<gblocks((long)E_AT + E_TA + E_AA), 256, 0, stream>>>(
        eat_d, eta_d, eaa_d, off_at, off_ta, off_aa);
    int nbT = (NT + 1023) / 1024, nbA = (NA + 1023) / 1024;
    k_scan1<<<nbT, 256, 0, stream>>>(off_at, NT, bsum);
    k_scan2<<<1, 256, 0, stream>>>(bsum, nbT, off_at, NT);
    k_scan3<<<nbT, 256, 0, stream>>>(off_at, NT, bsum, cur_at);
    k_scan1<<<nbA, 256, 0, stream>>>(off_ta, NA, bsum);
    k_scan2<<<1, 256, 0, stream>>>(bsum, nbA, off_ta, NA);
    k_scan3<<<nbA, 256, 0, stream>>>(off_ta, NA, bsum, cur_ta);
    k_scan1<<<nbA, 256, 0, stream>>>(off_aa, NA, bsum);
    k_scan2<<<1, 256, 0, stream>>>(bsum, nbA, off_aa, NA);
    k_scan3<<<nbA, 256, 0, stream>>>(off_aa, NA, bsum, cur_aa);
    k_scatter3<<<gblocks((long)E_AT + E_TA + E_AA), 256, 0, stream>>>(
        eat_s, eat_d, eta_s, eta_d, eaa_s, eaa_d,
        cur_at, cur_ta, cur_aa, csr_at, csr_ta, csr_aa);

    const int gA = (NA + 63) / 64, gT = (NT + 63) / 64;
    float* o_a1_prev = o_a1;
    float* o_a2_prev = o_a2;

    for (int l = 0; l < 3; l++) {
        if (l == 0) {
            k_proj_fused<64, true, 0><<<gA, 256, 0, stream>>>(
                x_addr, nullptr, nullptr, pW1, 0, pb1, 0, h_a, NA, attS, attD, 0,
                as0, ad1, as2, ad2, flagp);
            k_proj_fused<64, false, 0><<<gT, 256, 0, stream>>>(
                x_tx, nullptr, nullptr, pW1, 2048, pb1, 32, h_t, NT, attS, attD, 0,
                ad0, as1, nullptr, nullptr, flagp);
        } else {
            int wi = (l - 1) * 2;
            // addr input = relu(attn0*o_a1 + attn1*o_a2) fused into staging
            k_proj_fused<32, true, 2><<<gA, 256, 0, stream>>>(
                o_a1_prev, o_a2_prev, sem + 64, pW23, (wi + 0) * 1024, pb23, (wi + 0) * 32,
                h_a, NA, attS, attD, l * 96, as0, ad1, as2, ad2, flagp);
            // tx input = o_tx (R=1 semantic identity, already relu'd)
            k_proj_fused<32, false, 1><<<gT, 256, 0, stream>>>(
                o_tx, nullptr, nullptr, pW23, (wi + 1) * 1024, pb23, (wi + 1) * 32,
                h_t, NT, attS, attD, l * 96, ad0, as1, nullptr, nullptr, flagp);
        }
        // all 3 relation gathers in one dispatch
        k_gather3<<<gblocks((long)(NT + 2 * NA) * 32), 256, 0, stream>>>(
            off_at, csr_at, off_ta, csr_ta, off_aa, csr_aa,
            as0, ad0, as1, ad1, as2, ad2, h_a, h_t, o_tx, o_a1, o_a2);
        // semantic attention over {o_a1, o_a2}
        (void)hipMemsetAsync(sem, 0, 66 * sizeof(float), stream);
        k_sem_reduce2<<<gblocks(NA), 256, 0, stream>>>(o_a1, o_a2, NA, kW, l * 1024, kb, l * 32,
                                                       sem, flagp);
        k_sem_attn<<<1, 64, 0, stream>>>(sem, 1.0f / NA, qv, l * 32, sem + 64, flagp);
        if (l == 2) {
            k_combine_final<<<gblocks(NA), 256, 0, stream>>>(o_a1, o_a2, sem + 64,
                                                             linW, linb, d_out, NA, flagp);
        }
        o_a1_prev = o_a1;
        o_a2_prev = o_a2;
    }
}

// Round 5
// 987.551 us; speedup vs baseline: 8.1679x; 1.1594x over previous
//
#include <hip/hip_runtime.h>
#include <hip/hip_bf16.h>

#define NA 150000
#define NT 200000
#define E_AT 1000000
#define E_TA 1000000
#define E_AA 500000

#define CHK 16384          // edges per k_bin block
#define CAP 8192           // slot capacity per bin (max bin count ~3.8K)
#define P_AT 391           // ceil(NT/512)
#define P_TA 293           // ceil(NA/512)
#define P_AA 293
#define NBINS (P_AT + P_TA + P_AA)   // 977
#define CB_AT 62           // ceil(E_AT/CHK)
#define CB_TA 62
#define CB_AA 31

// ---------- dtype-flexible load: flag==1 -> fp32, flag==0 -> bf16 ----------
__device__ __forceinline__ float ldf(const void* p, long i, int f32) {
    if (f32) return ((const float*)p)[i];
    unsigned int u = ((const unsigned short*)p)[i];
    union { unsigned int ui; float f; } v; v.ui = u << 16;
    return v.f;
}
__device__ __forceinline__ float bf2f(unsigned short u) {
    union { unsigned int ui; float f; } v; v.ui = ((unsigned int)u) << 16;
    return v.f;
}
__device__ __forceinline__ float ftanh(float x) {
    x = fminf(fmaxf(x, -9.f), 9.f);
    float e = __expf(2.f * x);
    return (e - 1.f) / (e + 1.f);
}

// ---------- detect fp32 (1) vs bf16 (0) float inputs ----------
__global__ void k_detect(const void* __restrict__ x, int* __restrict__ flag) {
    __shared__ int cnt;
    if (threadIdx.x == 0) cnt = 0;
    __syncthreads();
    const unsigned short* u = (const unsigned short*)x;
    int wild = 0;
    for (int i = threadIdx.x; i < 4096; i += 256) {
        unsigned short v = u[i];
        int e = (v >> 7) & 0xFF;
        if (e > 133 || (e != 0 && e < 100)) wild++;
        else if (e == 0 && (v & 0x7F)) wild++;
    }
    atomicAdd(&cnt, wild);
    __syncthreads();
    if (threadIdx.x == 0) *flag = (cnt > 1024) ? 1 : 0;
}

// ========== fused projection + per-head attention dots ==========
// XMODE: 0 = global input (dtype-flagged), 1 = ws fp32, 2 = combine(o1,o2,attn)+relu
template<int K, bool ISADDR, int XMODE>
__global__ __launch_bounds__(256) void k_proj_fused(
        const void* __restrict__ X, const void* __restrict__ X2,
        const float* __restrict__ attn,
        const void* __restrict__ W, int wOff,
        const void* __restrict__ B, int bOff,
        float* __restrict__ H, int N,
        const void* __restrict__ attS, const void* __restrict__ attD, int lBase,
        float* __restrict__ a0p, float* __restrict__ a1p,
        float* __restrict__ a2p, float* __restrict__ a3p,
        const int* __restrict__ flagp) {
    constexpr int XS = K + 4;
    __shared__ float Ws[K * 32];
    __shared__ float Xs[64 * XS];
    const int f32 = *flagp;
    const int t = threadIdx.x;
    for (int i = t; i < K * 32; i += 256) Ws[i] = ldf(W, wOff + i, f32);
    const long n0 = (long)blockIdx.x * 64;
    constexpr int TOT4 = 64 * K / 4;
    if (XMODE == 2) {
        const float w0 = attn[0], w1 = attn[1];
        const float* Xa = (const float*)X;
        const float* Xb = (const float*)X2;
        for (int i = t; i < TOT4; i += 256) {
            int g = i * 4;
            int r = g / K, c = g & (K - 1);
            long gr = n0 + r; if (gr >= N) gr = N - 1;
            float4 va = *(const float4*)&Xa[gr * K + c];
            float4 vb = *(const float4*)&Xb[gr * K + c];
            float* dst = &Xs[r * XS + c];
            float v0 = w0 * va.x + w1 * vb.x;
            float v1 = w0 * va.y + w1 * vb.y;
            float v2 = w0 * va.z + w1 * vb.z;
            float v3 = w0 * va.w + w1 * vb.w;
            dst[0] = (v0 > 0.f) ? v0 : 0.f;
            dst[1] = (v1 > 0.f) ? v1 : 0.f;
            dst[2] = (v2 > 0.f) ? v2 : 0.f;
            dst[3] = (v3 > 0.f) ? v3 : 0.f;
        }
    } else if (XMODE == 1 || f32) {
        const float* Xf = (const float*)X;
        for (int i = t; i < TOT4; i += 256) {
            int g = i * 4;
            int r = g / K, c = g & (K - 1);
            long gr = n0 + r; if (gr >= N) gr = N - 1;
            float4 v = *(const float4*)&Xf[gr * K + c];
            float* dst = &Xs[r * XS + c];
            dst[0] = v.x; dst[1] = v.y; dst[2] = v.z; dst[3] = v.w;
        }
    } else {
        const unsigned short* Xh = (const unsigned short*)X;
        for (int i = t; i < TOT4; i += 256) {
            int g = i * 4;
            int r = g / K, c = g & (K - 1);
            long gr = n0 + r; if (gr >= N) gr = N - 1;
            ushort4 v = *(const ushort4*)&Xh[gr * K + c];
            float* dst = &Xs[r * XS + c];
            dst[0] = bf2f(v.x); dst[1] = bf2f(v.y); dst[2] = bf2f(v.z); dst[3] = bf2f(v.w);
        }
    }
    __syncthreads();
    const int nl = t >> 2, cg = t & 3;
    const long n = n0 + nl;
    float acc[8];
#pragma unroll
    for (int j = 0; j < 8; j++) acc[j] = ldf(B, bOff + cg * 8 + j, f32);
#pragma unroll
    for (int k = 0; k < K; k += 4) {
        float4 xv = *(const float4*)&Xs[nl * XS + k];
        const float x0 = xv.x, x1 = xv.y, x2 = xv.z, x3 = xv.w;
        const float* w0 = &Ws[(k + 0) * 32 + cg * 8];
        const float* w1 = &Ws[(k + 1) * 32 + cg * 8];
        const float* w2 = &Ws[(k + 2) * 32 + cg * 8];
        const float* w3 = &Ws[(k + 3) * 32 + cg * 8];
#pragma unroll
        for (int j = 0; j < 8; j++)
            acc[j] += x0 * w0[j] + x1 * w1[j] + x2 * w2[j] + x3 * w3[j];
    }
    if (n < N) {
        float* hp = &H[n * 32 + cg * 8];
        *(float4*)hp       = make_float4(acc[0], acc[1], acc[2], acc[3]);
        *(float4*)(hp + 4) = make_float4(acc[4], acc[5], acc[6], acc[7]);
        const int b = lBase + cg * 8;
        float d0 = 0.f, d1 = 0.f, d2 = 0.f, d3 = 0.f;
#pragma unroll
        for (int d = 0; d < 8; d++) {
            float x = acc[d];
            if (ISADDR) {
                d0 += x * ldf(attS, b + d, f32);
                d1 += x * ldf(attD, b + 32 + d, f32);
                d2 += x * ldf(attS, b + 64 + d, f32);
                d3 += x * ldf(attD, b + 64 + d, f32);
            } else {
                d0 += x * ldf(attD, b + d, f32);
                d1 += x * ldf(attS, b + 32 + d, f32);
            }
        }
        a0p[n * 4 + cg] = d0;
        a1p[n * 4 + cg] = d1;
        if (ISADDR) { a2p[n * 4 + cg] = d2; a3p[n * 4 + cg] = d3; }
    }
}

// ================= binned CSR build =================
// Phase A: bin edges by dst>>9 into fixed-capacity slots. pack = (ldst<<18)|src.
__global__ __launch_bounds__(256) void k_bin(
        const int* __restrict__ eat_s, const int* __restrict__ eat_d,
        const int* __restrict__ eta_s, const int* __restrict__ eta_d,
        const int* __restrict__ eaa_s, const int* __restrict__ eaa_d,
        int* __restrict__ gcnt,
        int* __restrict__ slot_at, int* __restrict__ slot_ta, int* __restrict__ slot_aa) {
    __shared__ int hist[P_AT];   // max bins per relation
    int b = blockIdx.x, t = threadIdx.x;
    const int *src, *dst; int E, P, seg; int* slot;
    if (b < CB_AT)              { src = eat_s; dst = eat_d; E = E_AT; P = P_AT; seg = 0;            slot = slot_at; }
    else if (b < CB_AT + CB_TA) { b -= CB_AT;  src = eta_s; dst = eta_d; E = E_TA; P = P_TA; seg = P_AT;        slot = slot_ta; }
    else                        { b -= CB_AT + CB_TA; src = eaa_s; dst = eaa_d; E = E_AA; P = P_AA; seg = P_AT + P_TA; slot = slot_aa; }
    long e0 = (long)b * CHK;
    for (int i = t; i < P; i += 256) hist[i] = 0;
    __syncthreads();
    for (int k = 0; k < CHK; k += 256) {
        long e = e0 + k + t;
        if (e < E) atomicAdd(&hist[dst[e] >> 9], 1);
    }
    __syncthreads();
    // reserve runs: hist[i] becomes this block's base cursor within bin i
    for (int i = t; i < P; i += 256) {
        int v = hist[i];
        hist[i] = atomicAdd(&gcnt[seg + i], v);
    }
    __syncthreads();
    for (int k = 0; k < CHK; k += 256) {
        long e = e0 + k + t;
        if (e < E) {
            int d = dst[e];
            int bin = d >> 9;
            int pos = atomicAdd(&hist[bin], 1);
            slot[bin * CAP + pos] = ((d & 511) << 18) | src[e];
        }
    }
}

// Phase A2: exclusive-scan bin counts per relation -> bin bases; write off[N].
__global__ void k_binscan(const int* __restrict__ gcnt, int* __restrict__ bbase,
                          int* __restrict__ off_at, int* __restrict__ off_ta,
                          int* __restrict__ off_aa) {
    __shared__ int sa[512], sb[512];
    int t = threadIdx.x;  // 512 threads
    const int segs[4] = {0, P_AT, P_AT + P_TA, NBINS};
    for (int r = 0; r < 3; r++) {
        int s0 = segs[r], P = segs[r + 1] - s0;
        sa[t] = (t < P) ? gcnt[s0 + t] : 0;
        __syncthreads();
        int* in = sa; int* out = sb;
        for (int o = 1; o < 512; o <<= 1) {
            out[t] = in[t] + (t >= o ? in[t - o] : 0);
            __syncthreads();
            int* tmp = in; in = out; out = tmp;
        }
        if (t < P) bbase[s0 + t] = (t ? in[t - 1] : 0);
        __syncthreads();
    }
    if (t == 0) { off_at[NT] = E_AT; off_ta[NA] = E_TA; off_aa[NA] = E_AA; }
}

// Phase B: per-bin LDS counting sort -> exact CSR + off. One block per bin;
// scattered csr writes stay inside a ~15 KB single-XCD window.
__global__ __launch_bounds__(256) void k_binsort(
        const int* __restrict__ gcnt, const int* __restrict__ bbase,
        const int* __restrict__ slot_at, const int* __restrict__ slot_ta,
        const int* __restrict__ slot_aa,
        int* __restrict__ off_at, int* __restrict__ off_ta, int* __restrict__ off_aa,
        int* __restrict__ csr_at, int* __restrict__ csr_ta, int* __restrict__ csr_aa) {
    __shared__ int sa[512], sb[512], cur[512];
    int b = blockIdx.x, t = threadIdx.x;
    const int* slot; int* off; int* csr; int N, bin, seg;
    if (b < P_AT)              { slot = slot_at; off = off_at; csr = csr_at; N = NT; bin = b;                seg = 0; }
    else if (b < P_AT + P_TA)  { slot = slot_ta; off = off_ta; csr = csr_ta; N = NA; bin = b - P_AT;         seg = P_AT; }
    else                       { slot = slot_aa; off = off_aa; csr = csr_aa; N = NA; bin = b - P_AT - P_TA;  seg = P_AT + P_TA; }
    const int cnt  = gcnt[seg + bin];
    const int base = bbase[seg + bin];
    const int* sp = &slot[bin * CAP];
    sa[t] = 0; sa[t + 256] = 0;
    __syncthreads();
    for (int i = t; i < cnt; i += 256) atomicAdd(&sa[sp[i] >> 18], 1);
    __syncthreads();
    int* in = sa; int* out = sb;
    for (int o = 1; o < 512; o <<= 1) {
        for (int i = t; i < 512; i += 256)
            out[i] = in[i] + (i >= o ? in[i - o] : 0);
        __syncthreads();
        int* tmp = in; in = out; out = tmp;
    }
    for (int i = t; i < 512; i += 256) {
        int excl = i ? in[i - 1] : 0;
        cur[i] = excl;
        int gd = bin * 512 + i;
        if (gd < N) off[gd] = base + excl;
    }
    __syncthreads();
    for (int i = t; i < cnt; i += 256) {
        int pk = sp[i];
        int pos = atomicAdd(&cur[pk >> 18], 1);
        csr[base + pos] = pk & 0x3FFFF;
    }
}

// ========== tri-relation gather: 32 lanes/dst, 4x unrolled edge loop ==========
__global__ __launch_bounds__(256) void k_gather3(
        const int* __restrict__ off_at, const int* __restrict__ csr_at,
        const int* __restrict__ off_ta, const int* __restrict__ csr_ta,
        const int* __restrict__ off_aa, const int* __restrict__ csr_aa,
        const float* __restrict__ as0, const float* __restrict__ ad0,
        const float* __restrict__ as1, const float* __restrict__ ad1,
        const float* __restrict__ as2, const float* __restrict__ ad2,
        const float* __restrict__ h_a, const float* __restrict__ h_t,
        float* __restrict__ o_tx, float* __restrict__ o_a1, float* __restrict__ o_a2) {
    int tid = blockIdx.x * blockDim.x + threadIdx.x;
    int u = tid >> 5;
    int j = tid & 31, h = j >> 3;
    const int *off, *csr;
    const float *as_, *ad_, *Hs;
    float* O;
    int n;
    if (u < NT) {
        n = u; off = off_at; csr = csr_at; as_ = as0; ad_ = ad0; Hs = h_a; O = o_tx;
    } else if (u < NT + NA) {
        n = u - NT; off = off_ta; csr = csr_ta; as_ = as1; ad_ = ad1; Hs = h_t; O = o_a1;
    } else if (u < NT + 2 * NA) {
        n = u - NT - NA; off = off_aa; csr = csr_aa; as_ = as2; ad_ = ad2; Hs = h_a; O = o_a2;
    } else return;
    float adv = ad_[n * 4 + h];
    int p0 = off[n], p1 = off[n + 1];
    float acc = 0.f, se = 0.f;
    int p = p0;
    for (; p + 4 <= p1; p += 4) {
        int s0 = csr[p], s1 = csr[p + 1], s2 = csr[p + 2], s3 = csr[p + 3];
        float A0 = as_[s0 * 4 + h], A1 = as_[s1 * 4 + h];
        float A2 = as_[s2 * 4 + h], A3 = as_[s3 * 4 + h];
        float H0 = Hs[s0 * 32 + j], H1 = Hs[s1 * 32 + j];
        float H2 = Hs[s2 * 32 + j], H3 = Hs[s3 * 32 + j];
        float l0 = A0 + adv; l0 = (l0 >= 0.f) ? l0 : 0.2f * l0; float e0 = __expf(l0);
        float l1 = A1 + adv; l1 = (l1 >= 0.f) ? l1 : 0.2f * l1; float e1 = __expf(l1);
        float l2 = A2 + adv; l2 = (l2 >= 0.f) ? l2 : 0.2f * l2; float e2 = __expf(l2);
        float l3 = A3 + adv; l3 = (l3 >= 0.f) ? l3 : 0.2f * l3; float e3 = __expf(l3);
        se += e0 + e1 + e2 + e3;
        acc += e0 * H0 + e1 * H1 + e2 * H2 + e3 * H3;
    }
    for (; p < p1; p++) {
        int s = csr[p];
        float l = as_[s * 4 + h] + adv;
        l = (l >= 0.f) ? l : 0.2f * l;
        float ev = __expf(l);
        se += ev;
        acc += ev * Hs[s * 32 + j];
    }
    float v = acc / (se + 1e-16f);
    O[n * 32 + j] = (v > 0.f) ? v : 0.f;
}

// ---------- fused dual semantic reduce ----------
__global__ void k_sem_reduce2(const float* __restrict__ O1, const float* __restrict__ O2, int N,
                              const void* __restrict__ kWp, int kwOff,
                              const void* __restrict__ kbp, int kbOff,
                              float* __restrict__ accum, const int* __restrict__ flagp) {
    int f32 = *flagp;
    __shared__ float w[1056];
    __shared__ float sacc[64];
    for (int i = threadIdx.x; i < 1024; i += blockDim.x) w[i] = ldf(kWp, kwOff + i, f32);
    if (threadIdx.x < 32) w[1024 + threadIdx.x] = ldf(kbp, kbOff + threadIdx.x, f32);
    if (threadIdx.x < 64) sacc[threadIdx.x] = 0.f;
    __syncthreads();
    int n = blockIdx.x * blockDim.x + threadIdx.x;
    const float* Os[2] = { O1, O2 };
#pragma unroll
    for (int r = 0; r < 2; r++) {
        float y[32];
        if (n < N) {
            float x[32];
#pragma unroll
            for (int k = 0; k < 32; k++) x[k] = Os[r][(long)n * 32 + k];
#pragma unroll
            for (int f = 0; f < 32; f++) {
                float acc = w[1024 + f];
#pragma unroll
                for (int k = 0; k < 32; k++) acc += x[k] * w[k * 32 + f];
                y[f] = ftanh(acc);
            }
        } else {
#pragma unroll
            for (int f = 0; f < 32; f++) y[f] = 0.f;
        }
#pragma unroll
        for (int f = 0; f < 32; f++) {
            float v = y[f];
            for (int o = 32; o > 0; o >>= 1) v += __shfl_xor(v, o, 64);
            if ((threadIdx.x & 63) == 0) atomicAdd(&sacc[r * 32 + f], v);
        }
    }
    __syncthreads();
    if (threadIdx.x < 64) atomicAdd(&accum[threadIdx.x], sacc[threadIdx.x]);
}

__global__ void k_sem_attn(const float* __restrict__ accum, float Ninv,
                           const void* __restrict__ q, int qOff,
                           float* __restrict__ attn, const int* __restrict__ flagp) {
    if (threadIdx.x == 0) {
        int f32 = *flagp;
        float s0 = 0.f, s1 = 0.f;
        for (int f = 0; f < 32; f++) {
            float qf = ldf(q, qOff + f, f32);
            s0 += accum[f] * Ninv * qf;
            s1 += accum[32 + f] * Ninv * qf;
        }
        float m = fmaxf(s0, s1);
        float e0 = __expf(s0 - m), e1 = __expf(s1 - m);
        float inv = 1.f / (e0 + e1);
        attn[0] = e0 * inv;
        attn[1] = e1 * inv;
    }
}

// ---------- fused combine + final linear (layer 3 only) ----------
__global__ void k_combine_final(const float* __restrict__ o1, const float* __restrict__ o2,
                                const float* __restrict__ attn,
                                const void* __restrict__ linW, const void* __restrict__ linb,
                                void* __restrict__ out, int N, const int* __restrict__ flagp) {
    int n = blockIdx.x * blockDim.x + threadIdx.x;
    if (n >= N) return;
    int f32 = *flagp;
    float w0 = attn[0], w1 = attn[1];
    float s0 = ldf(linb, 0, f32), s1 = ldf(linb, 1, f32);
    const float* p1 = &o1[(long)n * 32];
    const float* p2 = &o2[(long)n * 32];
#pragma unroll
    for (int f = 0; f < 32; f++) {
        float v = w0 * p1[f] + w1 * p2[f];
        v = (v > 0.f) ? v : 0.f;
        s0 += v * ldf(linW, f * 2, f32);
        s1 += v * ldf(linW, f * 2 + 1, f32);
    }
    if (f32) { ((float*)out)[n * 2] = s0; ((float*)out)[n * 2 + 1] = s1; }
    else {
        ((__hip_bfloat16*)out)[n * 2] = __float2bfloat16(s0);
        ((__hip_bfloat16*)out)[n * 2 + 1] = __float2bfloat16(s1);
    }
}

static inline int gblocks(long n) { return (int)((n + 255) / 256); }

extern "C" void kernel_launch(void* const* d_in, const int* in_sizes, int n_in,
                              void* d_out, int out_size, void* d_ws, size_t ws_size,
                              hipStream_t stream) {
    const void* x_addr = d_in[0];
    const void* x_tx   = d_in[1];
    const int* eat_s = (const int*)d_in[2];
    const int* eat_d = (const int*)d_in[3];
    const int* eta_s = (const int*)d_in[4];
    const int* eta_d = (const int*)d_in[5];
    const int* eaa_s = (const int*)d_in[6];
    const int* eaa_d = (const int*)d_in[7];
    const void* pW1  = d_in[8];
    const void* pb1  = d_in[9];
    const void* pW23 = d_in[10];
    const void* pb23 = d_in[11];
    const void* attS = d_in[12];
    const void* attD = d_in[13];
    const void* kW   = d_in[14];
    const void* kb   = d_in[15];
    const void* qv   = d_in[16];
    const void* linW = d_in[17];
    const void* linb = d_in[18];

    const size_t NA32 = (size_t)NA * 32, NT32 = (size_t)NT * 32;
    const size_t NA4 = (size_t)NA * 4, NT4 = (size_t)NT * 4;

    float* ws    = (float*)d_ws;
    float* h_a   = ws;
    float* h_t   = h_a + NA32;
    float* o_a1  = h_t + NT32;
    float* o_a2  = o_a1 + NA32;
    float* o_tx  = o_a2 + NA32;
    float* as0   = o_tx + NT32;
    float* ad1   = as0 + NA4;
    float* as2   = ad1 + NA4;
    float* ad2   = as2 + NA4;
    float* as1   = ad2 + NA4;
    float* ad0   = as1 + NT4;
    float* sem   = ad0 + NT4;            // 64 accum + 2 attn
    int*   flagp = (int*)(sem + 66);
    int*   off_at = flagp + 16;          // NT+1
    int*   off_ta = off_at + (NT + 1);   // NA+1
    int*   off_aa = off_ta + (NA + 1);   // NA+1
    int*   csr_at = off_aa + (NA + 1);   // E_AT
    int*   csr_ta = csr_at + E_AT;       // E_TA
    int*   csr_aa = csr_ta + E_TA;       // E_AA
    int*   gcnt   = csr_aa + E_AA;       // 1024
    int*   bbase  = gcnt + 1024;         // 1024
    int*   slot_at = bbase + 1024;       // P_AT*CAP
    int*   slot_ta = slot_at + P_AT * CAP;
    int*   slot_aa = slot_ta + P_TA * CAP;

    k_detect<<<1, 256, 0, stream>>>(x_addr, flagp);

    // ---- binned CSR build ----
    (void)hipMemsetAsync(gcnt, 0, 1024 * sizeof(int), stream);
    k_bin<<<CB_AT + CB_TA + CB_AA, 256, 0, stream>>>(
        eat_s, eat_d, eta_s, eta_d, eaa_s, eaa_d, gcnt, slot_at, slot_ta, slot_aa);
    k_binscan<<<1, 512, 0, stream>>>(gcnt, bbase, off_at, off_ta, off_aa);
    k_binsort<<<NBINS, 256, 0, stream>>>(gcnt, bbase, slot_at, slot_ta, slot_aa,
                                         off_at, off_ta, off_aa, csr_at, csr_ta, csr_aa);

    const int gA = (NA + 63) / 64, gT = (NT + 63) / 64;
    float* o_a1_prev = o_a1;
    float* o_a2_prev = o_a2;

    for (int l = 0; l < 3; l++) {
        if (l == 0) {
            k_proj_fused<64, true, 0><<<gA, 256, 0, stream>>>(
                x_addr, nullptr, nullptr, pW1, 0, pb1, 0, h_a, NA, attS, attD, 0,
                as0, ad1, as2, ad2, flagp);
            k_proj_fused<64, false, 0><<<gT, 256, 0, stream>>>(
                x_tx, nullptr, nullptr, pW1, 2048, pb1, 32, h_t, NT, attS, attD, 0,
                ad0, as1, nullptr, nullptr, flagp);
        } else {
            int wi = (l - 1) * 2;
            k_proj_fused<32, true, 2><<<gA, 256, 0, stream>>>(
                o_a1_prev, o_a2_prev, sem + 64, pW23, (wi + 0) * 1024, pb23, (wi + 0) * 32,
                h_a, NA, attS, attD, l * 96, as0, ad1, as2, ad2, flagp);
            k_proj_fused<32, false, 1><<<gT, 256, 0, stream>>>(
                o_tx, nullptr, nullptr, pW23, (wi + 1) * 1024, pb23, (wi + 1) * 32,
                h_t, NT, attS, attD, l * 96, ad0, as1, nullptr, nullptr, flagp);
        }
        k_gather3<<<gblocks((long)(NT + 2 * NA) * 32), 256, 0, stream>>>(
            off_at, csr_at, off_ta, csr_ta, off_aa, csr_aa,
            as0, ad0, as1, ad1, as2, ad2, h_a, h_t, o_tx, o_a1, o_a2);
        (void)hipMemsetAsync(sem, 0, 66 * sizeof(float), stream);
        k_sem_reduce2<<<gblocks(NA), 256, 0, stream>>>(o_a1, o_a2, NA, kW, l * 1024, kb, l * 32,
                                                       sem, flagp);
        k_sem_attn<<<1, 64, 0, stream>>>(sem, 1.0f / NA, qv, l * 32, sem + 64, flagp);
        if (l == 2) {
            k_combine_final<<<gblocks(NA), 256, 0, stream>>>(o_a1, o_a2, sem + 64,
                                                             linW, linb, d_out, NA, flagp);
        }
        o_a1_prev = o_a1;
        o_a2_prev = o_a2;
    }
}